// Round 8
// baseline (3094.153 us; speedup 1.0000x reference)
//
#include <hip/hip_runtime.h>

typedef __attribute__((ext_vector_type(8))) short bf16x8;
typedef __attribute__((ext_vector_type(4))) float f32x4;

#define S_LEN 256
#define VOCAB 32000
#define EMB   512
#define HID   1024

static const size_t OUT_H = 131072000ull; // probs floats before h_stack

__device__ inline unsigned short f2bf(float f) {
  unsigned int u = __float_as_uint(f);
  u = (u + 0x7FFFu + ((u >> 16) & 1u)) >> 16;
  return (unsigned short)u;
}
__device__ inline float bf2f(unsigned short s) {
  return __uint_as_float(((unsigned int)s) << 16);
}

// h store: agent-scope relaxed (sc1, write-through to coherence point)
__device__ inline void st_h(unsigned short* p, unsigned short v) {
  __hip_atomic_store(p, v, __ATOMIC_RELAXED, __HIP_MEMORY_SCOPE_AGENT);
}

// bijective XCD chunking (m204)
__device__ inline int xcd_swz(int o, int n) {
  int q = n >> 3, r = n & 7;
  int x = o & 7, i = o >> 3;
  return (x < r ? x * (q + 1) : r * (q + 1) + (x - r) * q) + i;
}

// ---------------- transpose + f32->bf16 : dst[N][K] = bf16(src[K][N]) ----------------
__global__ __launch_bounds__(256) void k_transpose_bf16(const float* __restrict__ src,
                                                        unsigned short* __restrict__ dst,
                                                        int K, int N) {
  __shared__ float tile[64][65];
  int n0 = blockIdx.x * 64, k0 = blockIdx.y * 64;
  int tid = threadIdx.x;
#pragma unroll
  for (int i = 0; i < 16; ++i) {
    int e = tid + i * 256;
    int r = e >> 6, c = e & 63;
    tile[r][c] = src[(size_t)(k0 + r) * N + n0 + c];
  }
  __syncthreads();
#pragma unroll
  for (int i = 0; i < 16; ++i) {
    int e = tid + i * 256;
    int r = e >> 6, c = e & 63;
    dst[(size_t)(n0 + r) * K + k0 + c] = f2bf(tile[c][r]);
  }
}

// ---------------- embedding gather -> bf16, rows r = s*16 + b ----------------
__global__ __launch_bounds__(256) void k_gather_emb(const int* __restrict__ tokens,
                                                    const float* __restrict__ emb,
                                                    unsigned short* __restrict__ Xg) {
  int r = blockIdx.x;
  int s = r >> 4, b = r & 15;
  int tok = tokens[b * S_LEN + s];
  const float* src = emb + (size_t)tok * EMB;
  int k = threadIdx.x * 2;
  float2 v = *(const float2*)(src + k);
  ushort2 o; o.x = f2bf(v.x); o.y = f2bf(v.y);
  *(ushort2*)(Xg + (size_t)r * EMB + k) = o;
}

// ---------------- bf16 GEMM: C = A @ BT^T + bias (f32 or bf16 out, opt softmax partials) ----
__device__ inline void gload16(const void* g, void* lds) {
  __builtin_amdgcn_global_load_lds((const __attribute__((address_space(1))) unsigned int*)g,
                                   (__attribute__((address_space(3))) unsigned int*)lds,
                                   16, 0, 0);
}

template <bool SMPART, bool BF16OUT>
__global__ __launch_bounds__(256) void k_gemm_bf16(const unsigned short* __restrict__ A,
                                                   const unsigned short* __restrict__ BT,
                                                   float* __restrict__ Cf,
                                                   unsigned short* __restrict__ Cb,
                                                   const float* __restrict__ bias,
                                                   int M, int N, int K,
                                                   float* __restrict__ Mpart,
                                                   float* __restrict__ Spart,
                                                   int NT) {
  __shared__ unsigned short As[4096]; // [4 kgrp][128 row][8]
  __shared__ unsigned short Bs[4096];
  __shared__ float redM[2][2][64];
  __shared__ float redS[2][2][64];
  int tid = threadIdx.x;
  int lane = tid & 63, wv = tid >> 6;
  int wr = wv >> 1, wc = wv & 1;
  int bxs = xcd_swz(blockIdx.x, gridDim.x);
  int am0 = blockIdx.y * 128, bn0 = bxs * 128;
  f32x4 zero = {0.f, 0.f, 0.f, 0.f};
  f32x4 acc[4][4];
#pragma unroll
  for (int m = 0; m < 4; ++m)
#pragma unroll
    for (int n = 0; n < 4; ++n) acc[m][n] = zero;
  int KT = K >> 5;
  int lr = lane & 15, kq = lane >> 4;
  for (int kt = 0; kt < KT; ++kt) {
    int k0 = kt << 5;
    __syncthreads();
#pragma unroll
    for (int c = 0; c < 2; ++c) {
      int t2 = c * 256 + tid;
      int row = t2 & 127, kg = t2 >> 7;
      gload16(A + (size_t)(am0 + row) * K + k0 + kg * 8, &As[(c * 256 + wv * 64) * 8]);
    }
#pragma unroll
    for (int c = 0; c < 2; ++c) {
      int t2 = c * 256 + tid;
      int row = t2 & 127, kg = t2 >> 7;
      gload16(BT + (size_t)(bn0 + row) * K + k0 + kg * 8, &Bs[(c * 256 + wv * 64) * 8]);
    }
    __syncthreads();
    const bf16x8* Ap = (const bf16x8*)As;
    const bf16x8* Bp = (const bf16x8*)Bs;
    bf16x8 af[4], bf[4];
#pragma unroll
    for (int m = 0; m < 4; ++m) af[m] = Ap[kq * 128 + wr * 64 + m * 16 + lr];
#pragma unroll
    for (int n = 0; n < 4; ++n) bf[n] = Bp[kq * 128 + wc * 64 + n * 16 + lr];
#pragma unroll
    for (int m = 0; m < 4; ++m)
#pragma unroll
      for (int n = 0; n < 4; ++n)
        acc[m][n] = __builtin_amdgcn_mfma_f32_16x16x32_bf16(af[m], bf[n], acc[m][n], 0, 0, 0);
  }
  float bvc[4];
#pragma unroll
  for (int n = 0; n < 4; ++n) {
    int col = bn0 + wc * 64 + n * 16 + lr;
    bvc[n] = bias ? bias[col] : 0.f;
  }
#pragma unroll
  for (int m = 0; m < 4; ++m)
#pragma unroll
    for (int n = 0; n < 4; ++n) {
      int col = bn0 + wc * 64 + n * 16 + lr;
#pragma unroll
      for (int q = 0; q < 4; ++q) {
        int row = am0 + wr * 64 + m * 16 + kq * 4 + q;
        if constexpr (BF16OUT)
          Cb[(size_t)row * N + col] = f2bf(acc[m][n][q] + bvc[n]);
        else
          Cf[(size_t)row * N + col] = acc[m][n][q] + bvc[n];
      }
    }
  if constexpr (SMPART) {
#pragma unroll
    for (int m = 0; m < 4; ++m)
#pragma unroll
      for (int q = 0; q < 4; ++q) {
        float mx = fmaxf(fmaxf(acc[m][0][q] + bvc[0], acc[m][1][q] + bvc[1]),
                         fmaxf(acc[m][2][q] + bvc[2], acc[m][3][q] + bvc[3]));
#pragma unroll
        for (int off = 1; off < 16; off <<= 1) mx = fmaxf(mx, __shfl_xor(mx, off));
        if (lr == 0) redM[wr][wc][m * 16 + kq * 4 + q] = mx;
      }
    __syncthreads();
#pragma unroll
    for (int m = 0; m < 4; ++m)
#pragma unroll
      for (int q = 0; q < 4; ++q) {
        int idx = m * 16 + kq * 4 + q;
        float mxF = fmaxf(redM[wr][0][idx], redM[wr][1][idx]);
        float s = __expf(acc[m][0][q] + bvc[0] - mxF) + __expf(acc[m][1][q] + bvc[1] - mxF) +
                  __expf(acc[m][2][q] + bvc[2] - mxF) + __expf(acc[m][3][q] + bvc[3] - mxF);
#pragma unroll
        for (int off = 1; off < 16; off <<= 1) s += __shfl_xor(s, off);
        if (lr == 0) redS[wr][wc][idx] = s;
      }
    __syncthreads();
    if (wc == 0 && lr == 0) {
#pragma unroll
      for (int m = 0; m < 4; ++m)
#pragma unroll
        for (int q = 0; q < 4; ++q) {
          int idx = m * 16 + kq * 4 + q;
          int row = am0 + wr * 64 + idx;
          Mpart[(size_t)row * NT + bxs] = fmaxf(redM[wr][0][idx], redM[wr][1][idx]);
          Spart[(size_t)row * NT + bxs] = redS[wr][0][idx] + redS[wr][1][idx];
        }
    }
  }
}

// ---------------- softmax combine: per-row M and 1/S from tile partials ----------------
__global__ __launch_bounds__(256) void k_sm_combine(const float* __restrict__ Mp,
                                                    const float* __restrict__ Sp,
                                                    float* __restrict__ MS, int T) {
  int row = blockIdx.x * 4 + (threadIdx.x >> 6);
  int lane = threadIdx.x & 63;
  float mx = -3.4e38f;
  for (int i = lane; i < T; i += 64) mx = fmaxf(mx, Mp[(size_t)row * T + i]);
#pragma unroll
  for (int o = 32; o > 0; o >>= 1) mx = fmaxf(mx, __shfl_xor(mx, o));
  float s = 0.f;
  for (int i = lane; i < T; i += 64)
    s += Sp[(size_t)row * T + i] * __expf(Mp[(size_t)row * T + i] - mx);
#pragma unroll
  for (int o = 32; o > 0; o >>= 1) s += __shfl_xor(s, o);
  if (lane == 0) { MS[row * 2] = mx; MS[row * 2 + 1] = 1.f / s; }
}

// ---------------- softmax apply (f32 in-place) ----------------
__global__ __launch_bounds__(256) void k_sm_apply(float* __restrict__ data,
                                                  const float* __restrict__ MS) {
  const int total = 4096 * (VOCAB / 4);
  for (int idx = blockIdx.x * 256 + threadIdx.x; idx < total; idx += gridDim.x * 256) {
    int row = idx / (VOCAB / 4);
    float M = MS[row * 2], inv = MS[row * 2 + 1];
    float4 v = ((const float4*)data)[idx];
    v.x = __expf(v.x - M) * inv;
    v.y = __expf(v.y - M) * inv;
    v.z = __expf(v.z - M) * inv;
    v.w = __expf(v.w - M) * inv;
    ((float4*)data)[idx] = v;
  }
}

// ---------------- softmax apply (bf16 logits -> f32 probs) ----------------
__global__ __launch_bounds__(256) void k_sm_apply_bf16(const unsigned short* __restrict__ lg,
                                                       float* __restrict__ probs,
                                                       const float* __restrict__ MS) {
  const int total = 4096 * (VOCAB / 4);
  for (int idx = blockIdx.x * 256 + threadIdx.x; idx < total; idx += gridDim.x * 256) {
    int row = idx / (VOCAB / 4);
    float M = MS[row * 2], inv = MS[row * 2 + 1];
    ushort4 v = ((const ushort4*)lg)[idx];
    float4 o;
    o.x = __expf(bf2f(v.x) - M) * inv;
    o.y = __expf(bf2f(v.y) - M) * inv;
    o.z = __expf(bf2f(v.z) - M) * inv;
    o.w = __expf(bf2f(v.w) - M) * inv;
    ((float4*)probs)[idx] = o;
  }
}

// ---------------- persistent 2-layer LSTM recurrence (batch-split pipelined) ----------------
struct LstmSmem {
  unsigned short U0s[16384]; // [128 kgrp][16 col][8] bf16
  unsigned short W1s[16384];
  unsigned short U1s[16384];
  float zA[4][16][16];
  float zB[4][16][16];
  float c0[16][4], h0f[16][4], c1[16][4], h1f[16][4];
  float b1s[16];
  short toks[16][256];
};

__global__ __launch_bounds__(256, 1) void k_lstm(const int* __restrict__ tokens,
                                                 const float* __restrict__ XW, // [256][16][4096]
                                                 const unsigned short* __restrict__ U0T,
                                                 const unsigned short* __restrict__ W1T,
                                                 const unsigned short* __restrict__ U1T,
                                                 const float* __restrict__ b1,
                                                 unsigned short* __restrict__ h0r, // [256][16][1024] rotating
                                                 unsigned short* __restrict__ h1r,
                                                 unsigned short* __restrict__ Y1,  // [16][256][1024]
                                                 float* outHC,
                                                 int* bar) {
  extern __shared__ char smraw[];
  LstmSmem& sm = *(LstmSmem*)smraw;
  int tid = threadIdx.x, bid = blockIdx.x;
  int lane = tid & 63, wv = tid >> 6;

  for (int idx = tid; idx < 2048; idx += 256) {
    int cidx = idx >> 7, kg = idx & 127;
    int gcol = (cidx >> 2) * 1024 + bid * 4 + (cidx & 3);
    *(uint4*)&sm.U0s[(kg * 16 + cidx) * 8] = *(const uint4*)&U0T[(size_t)gcol * 1024 + kg * 8];
    *(uint4*)&sm.W1s[(kg * 16 + cidx) * 8] = *(const uint4*)&W1T[(size_t)gcol * 1024 + kg * 8];
    *(uint4*)&sm.U1s[(kg * 16 + cidx) * 8] = *(const uint4*)&U1T[(size_t)gcol * 1024 + kg * 8];
  }
  for (int idx = tid; idx < 4096; idx += 256) {
    sm.toks[idx >> 8][idx & 255] = (short)tokens[idx];
  }
  if (tid < 64) {
    int b = tid >> 2, u = tid & 3;
    sm.c0[b][u] = 0.f; sm.h0f[b][u] = 0.f;
    sm.c1[b][u] = 0.f; sm.h1f[b][u] = 0.f;
  }
  if (tid < 16) sm.b1s[tid] = b1[(tid >> 2) * 1024 + bid * 4 + (tid & 3)];
  __syncthreads();

  int lr = lane & 15, kq = lane >> 4;
  int r8 = lane & 7; // A-fragment row within batch-half (rows 8..15 duplicate)
  int* flag0 = bar;
  int* flag1 = bar + 4096;

  // publish: syncthreads drains this block's sc1 h stores (vmcnt(0) before
  // s_barrier), then one private-line flag store certifies them at the MALL.
  auto publish = [&](int* base, int gen) {
    __syncthreads();
    if (tid == 0)
      __hip_atomic_store(&base[bid * 16], gen, __ATOMIC_RELAXED, __HIP_MEMORY_SCOPE_AGENT);
  };
  auto wait_flags = [&](int* base, int gen) {
    int ok;
    do {
      int f = __hip_atomic_load(&base[tid * 16], __ATOMIC_RELAXED, __HIP_MEMORY_SCOPE_AGENT);
      ok = (f >= gen);
    } while (!__syncthreads_and(ok));
  };

  // ---- prologue: step 0 layer-0 gates for all 16 batches, h0r[0] ----
  if (wv == 1) {
    int l = tid - 64, b = l >> 2, u = l & 3;
    const float* xp = XW + (size_t)b * 4096 + bid * 4 + u;
    float z0 = xp[0], z2 = xp[2048], z3 = xp[3072];
    float ii = 1.f / (1.f + expf(-z0));
    float gg = tanhf(z2);
    float oo = 1.f / (1.f + expf(-z3));
    float cn = ii * gg;
    float hn = oo * tanhf(cn);
    if (sm.toks[b][0] == 0) { cn = 0.f; hn = 0.f; }
    sm.c0[b][u] = cn; sm.h0f[b][u] = hn;
    st_h(h0r + b * HID + bid * 4 + u, f2bf(hn));
  }
  publish(flag0, 1);
  publish(flag1, 1);

  // one pipeline phase: stageB(t) + stageA(t+1) + gates for batch-half ph
  auto phase = [&](int ph, int t) {
    const unsigned short* h0t = h0r + (size_t)t * 16384 + ph * 8192;
    const unsigned short* h1p = h1r + (size_t)(t > 0 ? t - 1 : 0) * 16384 + ph * 8192;
    unsigned short* h1c = h1r + (size_t)t * 16384 + ph * 8192;
    unsigned short* h0n = h0r + (size_t)(t + 1) * 16384 + ph * 8192;

    float xwv0 = 0, xwv1 = 0, xwv2 = 0, xwv3 = 0;
    if (wv == 1 && lane < 32) { // prefetch next-step input projection for this half
      int b = ph * 8 + (lane >> 2), u = lane & 3;
      const float* xp = XW + ((size_t)(t + 1) * 16 + b) * 4096 + bid * 4 + u;
      xwv0 = xp[0]; xwv1 = xp[1024]; xwv2 = xp[2048]; xwv3 = xp[3072];
    }

    // stage B(t): z1 = [h0(t) ; h1(t-1)] @ [W1 ; U1], M=8 (rows 8..15 dup)
    f32x4 accB = {0.f, 0.f, 0.f, 0.f};
    {
      const unsigned short* ap = (wv < 2) ? h0t : h1p;
      const unsigned short* bm = (wv < 2) ? sm.W1s : sm.U1s;
      int kofs = (wv & 1) * 512;
      if (wv < 2 || t > 0) {
#pragma unroll
        for (int s8 = 0; s8 < 16; ++s8) {
          int kb = kofs + s8 * 32;
          bf16x8 av = *(const bf16x8*)(ap + r8 * HID + kb + kq * 8);
          bf16x8 bv = *(const bf16x8*)&bm[(((kb >> 3) + kq) * 16 + lr) * 8];
          accB = __builtin_amdgcn_mfma_f32_16x16x32_bf16(av, bv, accB, 0, 0, 0);
        }
      }
    }
    // stage A(t+1): z0 = h0(t) @ U0
    f32x4 accA = {0.f, 0.f, 0.f, 0.f};
#pragma unroll
    for (int s8 = 0; s8 < 8; ++s8) {
      int kb = wv * 256 + s8 * 32;
      bf16x8 av = *(const bf16x8*)(h0t + r8 * HID + kb + kq * 8);
      bf16x8 bv = *(const bf16x8*)&sm.U0s[(((kb >> 3) + kq) * 16 + lr) * 8];
      accA = __builtin_amdgcn_mfma_f32_16x16x32_bf16(av, bv, accA, 0, 0, 0);
    }
#pragma unroll
    for (int q = 0; q < 4; ++q) {
      sm.zB[wv][kq * 4 + q][lr] = accB[q];
      sm.zA[wv][kq * 4 + q][lr] = accA[q];
    }
    __syncthreads();

    if (tid < 32) { // layer-1 gates, time t, this half
      int bl = tid >> 2, u = tid & 3, b = ph * 8 + bl;
      int tok = sm.toks[b][t];
      float z0 = sm.b1s[0 + u]  + sm.zB[0][bl][0 + u]  + sm.zB[1][bl][0 + u]  + sm.zB[2][bl][0 + u]  + sm.zB[3][bl][0 + u];
      float z1 = sm.b1s[4 + u]  + sm.zB[0][bl][4 + u]  + sm.zB[1][bl][4 + u]  + sm.zB[2][bl][4 + u]  + sm.zB[3][bl][4 + u];
      float z2 = sm.b1s[8 + u]  + sm.zB[0][bl][8 + u]  + sm.zB[1][bl][8 + u]  + sm.zB[2][bl][8 + u]  + sm.zB[3][bl][8 + u];
      float z3 = sm.b1s[12 + u] + sm.zB[0][bl][12 + u] + sm.zB[1][bl][12 + u] + sm.zB[2][bl][12 + u] + sm.zB[3][bl][12 + u];
      float ii = 1.f / (1.f + expf(-z0));
      float ff = 1.f / (1.f + expf(-z1));
      float gg = tanhf(z2);
      float oo = 1.f / (1.f + expf(-z3));
      float cold = sm.c1[b][u], hold = sm.h1f[b][u];
      float cn = ff * cold + ii * gg;
      float hn = oo * tanhf(cn);
      if (tok == 0) { cn = cold; hn = hold; }
      sm.c1[b][u] = cn; sm.h1f[b][u] = hn;
      unsigned short hb = f2bf(hn);
      st_h(h1c + bl * HID + bid * 4 + u, hb);
      Y1[((size_t)b * S_LEN + t) * HID + bid * 4 + u] = hb; // plain: kernel-end flush
    } else if (wv == 1 && lane < 32) { // layer-0 gates, time t+1, this half
      int bl = lane >> 2, u = lane & 3, b = ph * 8 + bl;
      int tok = sm.toks[b][t + 1];
      float z0 = xwv0 + sm.zA[0][bl][0 + u]  + sm.zA[1][bl][0 + u]  + sm.zA[2][bl][0 + u]  + sm.zA[3][bl][0 + u];
      float z1 = xwv1 + sm.zA[0][bl][4 + u]  + sm.zA[1][bl][4 + u]  + sm.zA[2][bl][4 + u]  + sm.zA[3][bl][4 + u];
      float z2 = xwv2 + sm.zA[0][bl][8 + u]  + sm.zA[1][bl][8 + u]  + sm.zA[2][bl][8 + u]  + sm.zA[3][bl][8 + u];
      float z3 = xwv3 + sm.zA[0][bl][12 + u] + sm.zA[1][bl][12 + u] + sm.zA[2][bl][12 + u] + sm.zA[3][bl][12 + u];
      float ii = 1.f / (1.f + expf(-z0));
      float ff = 1.f / (1.f + expf(-z1));
      float gg = tanhf(z2);
      float oo = 1.f / (1.f + expf(-z3));
      float cold = sm.c0[b][u], hold = sm.h0f[b][u];
      float cn = ff * cold + ii * gg;
      float hn = oo * tanhf(cn);
      if (tok == 0) { cn = cold; hn = hold; }
      sm.c0[b][u] = cn; sm.h0f[b][u] = hn;
      st_h(h0n + bl * HID + bid * 4 + u, f2bf(hn));
    }
  };

  // ---- main loop: each half's chain = publish -> V -> compute(C/2) -> publish ----
  for (int t = 0; t < 255; ++t) {
    wait_flags(flag0, t + 1);
    phase(0, t);
    publish(flag0, t + 2);
    wait_flags(flag1, t + 1);
    phase(1, t);
    publish(flag1, t + 2);
  }

  // ---- epilogue: stage B(255) + layer-1 gates, per half ----
  auto phaseEp = [&](int ph) {
    const unsigned short* h0t = h0r + 255ull * 16384 + ph * 8192;
    const unsigned short* h1p = h1r + 254ull * 16384 + ph * 8192;
    f32x4 accB = {0.f, 0.f, 0.f, 0.f};
    const unsigned short* ap = (wv < 2) ? h0t : h1p;
    const unsigned short* bm = (wv < 2) ? sm.W1s : sm.U1s;
    int kofs = (wv & 1) * 512;
#pragma unroll
    for (int s8 = 0; s8 < 16; ++s8) {
      int kb = kofs + s8 * 32;
      bf16x8 av = *(const bf16x8*)(ap + r8 * HID + kb + kq * 8);
      bf16x8 bv = *(const bf16x8*)&bm[(((kb >> 3) + kq) * 16 + lr) * 8];
      accB = __builtin_amdgcn_mfma_f32_16x16x32_bf16(av, bv, accB, 0, 0, 0);
    }
#pragma unroll
    for (int q = 0; q < 4; ++q) sm.zB[wv][kq * 4 + q][lr] = accB[q];
    __syncthreads();
    if (tid < 32) {
      int bl = tid >> 2, u = tid & 3, b = ph * 8 + bl;
      int tok = sm.toks[b][255];
      float z0 = sm.b1s[0 + u]  + sm.zB[0][bl][0 + u]  + sm.zB[1][bl][0 + u]  + sm.zB[2][bl][0 + u]  + sm.zB[3][bl][0 + u];
      float z1 = sm.b1s[4 + u]  + sm.zB[0][bl][4 + u]  + sm.zB[1][bl][4 + u]  + sm.zB[2][bl][4 + u]  + sm.zB[3][bl][4 + u];
      float z2 = sm.b1s[8 + u]  + sm.zB[0][bl][8 + u]  + sm.zB[1][bl][8 + u]  + sm.zB[2][bl][8 + u]  + sm.zB[3][bl][8 + u];
      float z3 = sm.b1s[12 + u] + sm.zB[0][bl][12 + u] + sm.zB[1][bl][12 + u] + sm.zB[2][bl][12 + u] + sm.zB[3][bl][12 + u];
      float ii = 1.f / (1.f + expf(-z0));
      float ff = 1.f / (1.f + expf(-z1));
      float gg = tanhf(z2);
      float oo = 1.f / (1.f + expf(-z3));
      float cold = sm.c1[b][u], hold = sm.h1f[b][u];
      float cn = ff * cold + ii * gg;
      float hn = oo * tanhf(cn);
      if (tok == 0) { cn = cold; hn = hold; }
      sm.c1[b][u] = cn; sm.h1f[b][u] = hn;
      Y1[((size_t)b * S_LEN + 255) * HID + bid * 4 + u] = f2bf(hn);
    }
    __syncthreads();
  };
  wait_flags(flag0, 256);
  phaseEp(0);
  wait_flags(flag1, 256);
  phaseEp(1);

  if (tid < 64) {
    int b = tid >> 2, u = tid & 3, ug = bid * 4 + u;
    outHC[OUT_H + (size_t)b * HID + ug]         = sm.h0f[b][u];
    outHC[OUT_H + 16384 + (size_t)b * HID + ug] = sm.h1f[b][u];
    outHC[OUT_H + 32768 + (size_t)b * HID + ug] = sm.c0[b][u];
    outHC[OUT_H + 49152 + (size_t)b * HID + ug] = sm.c1[b][u];
  }
}

extern "C" void kernel_launch(void* const* d_in, const int* in_sizes, int n_in,
                              void* d_out, int out_size, void* d_ws, size_t ws_size,
                              hipStream_t stream) {
  const int*   tokens = (const int*)d_in[0];
  const float* emb = (const float*)d_in[1];
  const float* W0  = (const float*)d_in[2];
  const float* U0  = (const float*)d_in[3];
  const float* b0  = (const float*)d_in[4];
  const float* W1  = (const float*)d_in[5];
  const float* U1  = (const float*)d_in[6];
  const float* b1  = (const float*)d_in[7];
  const float* Wd  = (const float*)d_in[8];
  const float* bd  = (const float*)d_in[9];
  float* out = (float*)d_out;

  char* ws = (char*)d_ws;
  size_t off = 0;
  auto alloc = [&](size_t bytes) { char* p = ws + off; off += (bytes + 255) & ~(size_t)255; return p; };
  unsigned short* W0T = (unsigned short*)alloc(4096ull * 512 * 2);
  unsigned short* U0T = (unsigned short*)alloc(4096ull * 1024 * 2);
  unsigned short* W1T = (unsigned short*)alloc(4096ull * 1024 * 2);
  unsigned short* U1T = (unsigned short*)alloc(4096ull * 1024 * 2);
  unsigned short* WdT = (unsigned short*)alloc(32000ull * 1024 * 2);
  unsigned short* Xg  = (unsigned short*)alloc(4096ull * 512 * 2);
  unsigned short* Y1  = (unsigned short*)alloc(4096ull * 1024 * 2);
  int*   bar   = (int*)alloc(32768);            // 2 flag arrays x 256 x 64B lines
  float* Mpart = (float*)alloc(4096ull * 250 * 4);
  float* Spart = (float*)alloc(4096ull * 250 * 4);
  float* MS    = (float*)alloc(4096ull * 2 * 4);
  // bf16 logits buffer only if workspace allows (runtime guard; else f32 in-place)
  unsigned short* Lb = nullptr;
  if (ws_size >= off + 4096ull * VOCAB * 2 + 256)
    Lb = (unsigned short*)alloc(4096ull * VOCAB * 2);

  float* XW = out; // 64 MB scratch inside probs region (dead before decoder writes)
  unsigned short* h0r = (unsigned short*)((char*)d_out + 192ull * 1024 * 1024);
  unsigned short* h1r = (unsigned short*)((char*)d_out + 208ull * 1024 * 1024);

  hipMemsetAsync(bar, 0, 32768, stream); // reset flags every launch (graph-replay safe)

  hipFuncSetAttribute((const void*)k_lstm, hipFuncAttributeMaxDynamicSharedMemorySize,
                      (int)sizeof(LstmSmem));

  k_transpose_bf16<<<dim3(64, 8), 256, 0, stream>>>(W0, W0T, 512, 4096);
  k_transpose_bf16<<<dim3(64, 16), 256, 0, stream>>>(U0, U0T, 1024, 4096);
  k_transpose_bf16<<<dim3(64, 16), 256, 0, stream>>>(W1, W1T, 1024, 4096);
  k_transpose_bf16<<<dim3(64, 16), 256, 0, stream>>>(U1, U1T, 1024, 4096);
  k_transpose_bf16<<<dim3(500, 16), 256, 0, stream>>>(Wd, WdT, 1024, 32000);
  k_gather_emb<<<4096, 256, 0, stream>>>(tokens, emb, Xg);

  // XW[s*16+b][4096] = x @ W0 + b0
  k_gemm_bf16<false, false><<<dim3(32, 32), 256, 0, stream>>>(Xg, W0T, XW, nullptr, b0,
                                                              4096, 4096, 512,
                                                              nullptr, nullptr, 0);

  k_lstm<<<256, 256, sizeof(LstmSmem), stream>>>(tokens, XW, U0T, W1T, U1T, b1,
                                                 h0r, h1r, Y1, out, bar);

  // logits = Y1 @ Wd + bd, with fused softmax partials
  if (Lb) {
    k_gemm_bf16<true, true><<<dim3(250, 32), 256, 0, stream>>>(Y1, WdT, nullptr, Lb, bd,
                                                               4096, 32000, 1024,
                                                               Mpart, Spart, 250);
    k_sm_combine<<<1024, 256, 0, stream>>>(Mpart, Spart, MS, 250);
    k_sm_apply_bf16<<<4096, 256, 0, stream>>>(Lb, out, MS);
  } else {
    k_gemm_bf16<true, false><<<dim3(250, 32), 256, 0, stream>>>(Y1, WdT, out, nullptr, bd,
                                                                4096, 32000, 1024,
                                                                Mpart, Spart, 250);
    k_sm_combine<<<1024, 256, 0, stream>>>(Mpart, Spart, MS, 250);
    k_sm_apply<<<4096, 256, 0, stream>>>(out, MS);
  }
}

// Round 9
// 2362.544 us; speedup vs baseline: 1.3097x; 1.3097x over previous
//
#include <hip/hip_runtime.h>

typedef __attribute__((ext_vector_type(8))) short bf16x8;
typedef __attribute__((ext_vector_type(4))) float f32x4;

#define S_LEN 256
#define VOCAB 32000
#define EMB   512
#define HID   1024

static const size_t OUT_H = 131072000ull; // probs floats before h_stack

__device__ inline unsigned short f2bf(float f) {
  unsigned int u = __float_as_uint(f);
  u = (u + 0x7FFFu + ((u >> 16) & 1u)) >> 16;
  return (unsigned short)u;
}
__device__ inline float bf2f(unsigned short s) {
  return __uint_as_float(((unsigned int)s) << 16);
}

// h store: agent-scope relaxed (sc1, write-through to coherence point)
__device__ inline void st_h(unsigned short* p, unsigned short v) {
  __hip_atomic_store(p, v, __ATOMIC_RELAXED, __HIP_MEMORY_SCOPE_AGENT);
}

// bijective XCD chunking (m204)
__device__ inline int xcd_swz(int o, int n) {
  int q = n >> 3, r = n & 7;
  int x = o & 7, i = o >> 3;
  return (x < r ? x * (q + 1) : r * (q + 1) + (x - r) * q) + i;
}

// ---------------- transpose + f32->bf16 : dst[N][K] = bf16(src[K][N]) ----------------
__global__ __launch_bounds__(256) void k_transpose_bf16(const float* __restrict__ src,
                                                        unsigned short* __restrict__ dst,
                                                        int K, int N) {
  __shared__ float tile[64][65];
  int n0 = blockIdx.x * 64, k0 = blockIdx.y * 64;
  int tid = threadIdx.x;
#pragma unroll
  for (int i = 0; i < 16; ++i) {
    int e = tid + i * 256;
    int r = e >> 6, c = e & 63;
    tile[r][c] = src[(size_t)(k0 + r) * N + n0 + c];
  }
  __syncthreads();
#pragma unroll
  for (int i = 0; i < 16; ++i) {
    int e = tid + i * 256;
    int r = e >> 6, c = e & 63;
    dst[(size_t)(n0 + r) * K + k0 + c] = f2bf(tile[c][r]);
  }
}

// ---------------- embedding gather -> bf16, rows r = s*16 + b ----------------
__global__ __launch_bounds__(256) void k_gather_emb(const int* __restrict__ tokens,
                                                    const float* __restrict__ emb,
                                                    unsigned short* __restrict__ Xg) {
  int r = blockIdx.x;
  int s = r >> 4, b = r & 15;
  int tok = tokens[b * S_LEN + s];
  const float* src = emb + (size_t)tok * EMB;
  int k = threadIdx.x * 2;
  float2 v = *(const float2*)(src + k);
  ushort2 o; o.x = f2bf(v.x); o.y = f2bf(v.y);
  *(ushort2*)(Xg + (size_t)r * EMB + k) = o;
}

// ---------------- bf16 GEMM: C = A @ BT^T + bias (f32 or bf16 out, opt softmax partials) ----
__device__ inline void gload16(const void* g, void* lds) {
  __builtin_amdgcn_global_load_lds((const __attribute__((address_space(1))) unsigned int*)g,
                                   (__attribute__((address_space(3))) unsigned int*)lds,
                                   16, 0, 0);
}

template <bool SMPART, bool BF16OUT>
__global__ __launch_bounds__(256) void k_gemm_bf16(const unsigned short* __restrict__ A,
                                                   const unsigned short* __restrict__ BT,
                                                   float* __restrict__ Cf,
                                                   unsigned short* __restrict__ Cb,
                                                   const float* __restrict__ bias,
                                                   int M, int N, int K,
                                                   float* __restrict__ Mpart,
                                                   float* __restrict__ Spart,
                                                   int NT) {
  __shared__ unsigned short As[4096]; // [4 kgrp][128 row][8]
  __shared__ unsigned short Bs[4096];
  __shared__ float redM[2][2][64];
  __shared__ float redS[2][2][64];
  int tid = threadIdx.x;
  int lane = tid & 63, wv = tid >> 6;
  int wr = wv >> 1, wc = wv & 1;
  int bxs = xcd_swz(blockIdx.x, gridDim.x);
  int am0 = blockIdx.y * 128, bn0 = bxs * 128;
  f32x4 zero = {0.f, 0.f, 0.f, 0.f};
  f32x4 acc[4][4];
#pragma unroll
  for (int m = 0; m < 4; ++m)
#pragma unroll
    for (int n = 0; n < 4; ++n) acc[m][n] = zero;
  int KT = K >> 5;
  int lr = lane & 15, kq = lane >> 4;
  for (int kt = 0; kt < KT; ++kt) {
    int k0 = kt << 5;
    __syncthreads();
#pragma unroll
    for (int c = 0; c < 2; ++c) {
      int t2 = c * 256 + tid;
      int row = t2 & 127, kg = t2 >> 7;
      gload16(A + (size_t)(am0 + row) * K + k0 + kg * 8, &As[(c * 256 + wv * 64) * 8]);
    }
#pragma unroll
    for (int c = 0; c < 2; ++c) {
      int t2 = c * 256 + tid;
      int row = t2 & 127, kg = t2 >> 7;
      gload16(BT + (size_t)(bn0 + row) * K + k0 + kg * 8, &Bs[(c * 256 + wv * 64) * 8]);
    }
    __syncthreads();
    const bf16x8* Ap = (const bf16x8*)As;
    const bf16x8* Bp = (const bf16x8*)Bs;
    bf16x8 af[4], bf[4];
#pragma unroll
    for (int m = 0; m < 4; ++m) af[m] = Ap[kq * 128 + wr * 64 + m * 16 + lr];
#pragma unroll
    for (int n = 0; n < 4; ++n) bf[n] = Bp[kq * 128 + wc * 64 + n * 16 + lr];
#pragma unroll
    for (int m = 0; m < 4; ++m)
#pragma unroll
      for (int n = 0; n < 4; ++n)
        acc[m][n] = __builtin_amdgcn_mfma_f32_16x16x32_bf16(af[m], bf[n], acc[m][n], 0, 0, 0);
  }
  float bvc[4];
#pragma unroll
  for (int n = 0; n < 4; ++n) {
    int col = bn0 + wc * 64 + n * 16 + lr;
    bvc[n] = bias ? bias[col] : 0.f;
  }
#pragma unroll
  for (int m = 0; m < 4; ++m)
#pragma unroll
    for (int n = 0; n < 4; ++n) {
      int col = bn0 + wc * 64 + n * 16 + lr;
#pragma unroll
      for (int q = 0; q < 4; ++q) {
        int row = am0 + wr * 64 + m * 16 + kq * 4 + q;
        if constexpr (BF16OUT)
          Cb[(size_t)row * N + col] = f2bf(acc[m][n][q] + bvc[n]);
        else
          Cf[(size_t)row * N + col] = acc[m][n][q] + bvc[n];
      }
    }
  if constexpr (SMPART) {
#pragma unroll
    for (int m = 0; m < 4; ++m)
#pragma unroll
      for (int q = 0; q < 4; ++q) {
        float mx = fmaxf(fmaxf(acc[m][0][q] + bvc[0], acc[m][1][q] + bvc[1]),
                         fmaxf(acc[m][2][q] + bvc[2], acc[m][3][q] + bvc[3]));
#pragma unroll
        for (int off = 1; off < 16; off <<= 1) mx = fmaxf(mx, __shfl_xor(mx, off));
        if (lr == 0) redM[wr][wc][m * 16 + kq * 4 + q] = mx;
      }
    __syncthreads();
#pragma unroll
    for (int m = 0; m < 4; ++m)
#pragma unroll
      for (int q = 0; q < 4; ++q) {
        int idx = m * 16 + kq * 4 + q;
        float mxF = fmaxf(redM[wr][0][idx], redM[wr][1][idx]);
        float s = __expf(acc[m][0][q] + bvc[0] - mxF) + __expf(acc[m][1][q] + bvc[1] - mxF) +
                  __expf(acc[m][2][q] + bvc[2] - mxF) + __expf(acc[m][3][q] + bvc[3] - mxF);
#pragma unroll
        for (int off = 1; off < 16; off <<= 1) s += __shfl_xor(s, off);
        if (lr == 0) redS[wr][wc][idx] = s;
      }
    __syncthreads();
    if (wc == 0 && lr == 0) {
#pragma unroll
      for (int m = 0; m < 4; ++m)
#pragma unroll
        for (int q = 0; q < 4; ++q) {
          int idx = m * 16 + kq * 4 + q;
          int row = am0 + wr * 64 + idx;
          Mpart[(size_t)row * NT + bxs] = fmaxf(redM[wr][0][idx], redM[wr][1][idx]);
          Spart[(size_t)row * NT + bxs] = redS[wr][0][idx] + redS[wr][1][idx];
        }
    }
  }
}

// ---------------- softmax combine: per-row M and 1/S from tile partials ----------------
__global__ __launch_bounds__(256) void k_sm_combine(const float* __restrict__ Mp,
                                                    const float* __restrict__ Sp,
                                                    float* __restrict__ MS, int T) {
  int row = blockIdx.x * 4 + (threadIdx.x >> 6);
  int lane = threadIdx.x & 63;
  float mx = -3.4e38f;
  for (int i = lane; i < T; i += 64) mx = fmaxf(mx, Mp[(size_t)row * T + i]);
#pragma unroll
  for (int o = 32; o > 0; o >>= 1) mx = fmaxf(mx, __shfl_xor(mx, o));
  float s = 0.f;
  for (int i = lane; i < T; i += 64)
    s += Sp[(size_t)row * T + i] * __expf(Mp[(size_t)row * T + i] - mx);
#pragma unroll
  for (int o = 32; o > 0; o >>= 1) s += __shfl_xor(s, o);
  if (lane == 0) { MS[row * 2] = mx; MS[row * 2 + 1] = 1.f / s; }
}

// ---------------- softmax apply (f32 in-place) ----------------
__global__ __launch_bounds__(256) void k_sm_apply(float* __restrict__ data,
                                                  const float* __restrict__ MS) {
  const int total = 4096 * (VOCAB / 4);
  for (int idx = blockIdx.x * 256 + threadIdx.x; idx < total; idx += gridDim.x * 256) {
    int row = idx / (VOCAB / 4);
    float M = MS[row * 2], inv = MS[row * 2 + 1];
    float4 v = ((const float4*)data)[idx];
    v.x = __expf(v.x - M) * inv;
    v.y = __expf(v.y - M) * inv;
    v.z = __expf(v.z - M) * inv;
    v.w = __expf(v.w - M) * inv;
    ((float4*)data)[idx] = v;
  }
}

// ---------------- softmax apply (bf16 logits -> f32 probs) ----------------
__global__ __launch_bounds__(256) void k_sm_apply_bf16(const unsigned short* __restrict__ lg,
                                                       float* __restrict__ probs,
                                                       const float* __restrict__ MS) {
  const int total = 4096 * (VOCAB / 4);
  for (int idx = blockIdx.x * 256 + threadIdx.x; idx < total; idx += gridDim.x * 256) {
    int row = idx / (VOCAB / 4);
    float M = MS[row * 2], inv = MS[row * 2 + 1];
    ushort4 v = ((const ushort4*)lg)[idx];
    float4 o;
    o.x = __expf(bf2f(v.x) - M) * inv;
    o.y = __expf(bf2f(v.y) - M) * inv;
    o.z = __expf(bf2f(v.z) - M) * inv;
    o.w = __expf(bf2f(v.w) - M) * inv;
    ((float4*)probs)[idx] = o;
  }
}

// ---------------- persistent 2-layer LSTM recurrence ----------------
struct LstmSmem {
  unsigned short U0s[16384]; // [128 kgrp][16 col][8] bf16
  unsigned short W1s[16384];
  unsigned short U1s[16384];
  float zA[4][16][16];
  float zB[4][16][16];
  float c0[16][4], h0f[16][4], c1[16][4], h1f[16][4];
  float b1s[16];
  short toks[16][256];
  unsigned short h0st[16][4], h1st[16][4]; // bf16 staging for wide publication
};

__global__ __launch_bounds__(256, 1) void k_lstm(const int* __restrict__ tokens,
                                                 const float* __restrict__ XW, // [256][16][4096]
                                                 const unsigned short* __restrict__ U0T,
                                                 const unsigned short* __restrict__ W1T,
                                                 const unsigned short* __restrict__ U1T,
                                                 const float* __restrict__ b1,
                                                 unsigned short* __restrict__ h0r, // [256][16][1024] rotating
                                                 unsigned short* __restrict__ h1r,
                                                 unsigned short* __restrict__ Y1,  // [16][256][1024]
                                                 float* outHC,
                                                 int* bar) {
  extern __shared__ char smraw[];
  LstmSmem& sm = *(LstmSmem*)smraw;
  int tid = threadIdx.x, bid = blockIdx.x;
  int lane = tid & 63, wv = tid >> 6;

  for (int idx = tid; idx < 2048; idx += 256) {
    int cidx = idx >> 7, kg = idx & 127;
    int gcol = (cidx >> 2) * 1024 + bid * 4 + (cidx & 3);
    *(uint4*)&sm.U0s[(kg * 16 + cidx) * 8] = *(const uint4*)&U0T[(size_t)gcol * 1024 + kg * 8];
    *(uint4*)&sm.W1s[(kg * 16 + cidx) * 8] = *(const uint4*)&W1T[(size_t)gcol * 1024 + kg * 8];
    *(uint4*)&sm.U1s[(kg * 16 + cidx) * 8] = *(const uint4*)&U1T[(size_t)gcol * 1024 + kg * 8];
  }
  for (int idx = tid; idx < 4096; idx += 256) {
    sm.toks[idx >> 8][idx & 255] = (short)tokens[idx];
  }
  if (tid < 64) {
    int b = tid >> 2, u = tid & 3;
    sm.c0[b][u] = 0.f; sm.h0f[b][u] = 0.f;
    sm.c1[b][u] = 0.f; sm.h1f[b][u] = 0.f;
  }
  if (tid < 16) sm.b1s[tid] = b1[(tid >> 2) * 1024 + bid * 4 + (tid & 3)];
  __syncthreads();

  int lr = lane & 15, kq = lane >> 4;

  // grid barrier: per-block flag on a PRIVATE 64B line + all-flags poll.
  // Wave 0 issues ALL h stores (wide 8B) AND the flag store: the compiler's
  // vmcnt(0) before s_barrier orders the h stores before the flag within the
  // same wave -- tightest drain->flag chain. flag[bid]=gen certifies this
  // block's h stores are at the coherence point.
  auto gbar = [&](int gen) {
    __syncthreads();
    if (tid == 0)
      __hip_atomic_store(&bar[bid * 16], gen, __ATOMIC_RELAXED, __HIP_MEMORY_SCOPE_AGENT);
    int ok;
    do {
      int f = __hip_atomic_load(&bar[tid * 16], __ATOMIC_RELAXED, __HIP_MEMORY_SCOPE_AGENT);
      ok = (f >= gen);
    } while (!__syncthreads_and(ok));
  };

  // ---- prologue: step 0 layer-0 gates (recurrent term = 0), h0r[0] ----
  if (wv == 1) {
    int l = tid - 64, b = l >> 2, u = l & 3;
    const float* xp = XW + (size_t)b * 4096 + bid * 4 + u;
    float z0 = xp[0], z2 = xp[2048], z3 = xp[3072];
    float ii = 1.f / (1.f + expf(-z0));
    float gg = tanhf(z2);
    float oo = 1.f / (1.f + expf(-z3));
    float cn = ii * gg;
    float hn = oo * tanhf(cn);
    if (sm.toks[b][0] == 0) { cn = 0.f; hn = 0.f; }
    sm.c0[b][u] = cn; sm.h0f[b][u] = hn;
    st_h(h0r + b * HID + bid * 4 + u, f2bf(hn));
  }
  gbar(1);

  // ---- main loop: body t = stageB(t) + stageA(t+1), one barrier/step ----
  for (int t = 0; t < 255; ++t) {
    const unsigned short* h0t = h0r + (size_t)t * 16384;
    const unsigned short* h1p = h1r + (size_t)(t > 0 ? t - 1 : 0) * 16384;
    unsigned short* h1c = h1r + (size_t)t * 16384;
    unsigned short* h0n = h0r + (size_t)(t + 1) * 16384;

    float xwv0 = 0, xwv1 = 0, xwv2 = 0, xwv3 = 0;
    if (wv == 1) {
      int l = tid - 64, b = l >> 2, u = l & 3;
      const float* xp = XW + ((size_t)(t + 1) * 16 + b) * 4096 + bid * 4 + u;
      xwv0 = xp[0]; xwv1 = xp[1024]; xwv2 = xp[2048]; xwv3 = xp[3072];
    }

    // stage B(t): z1 = [h0(t) ; h1(t-1)] @ [W1 ; U1]
    f32x4 accB = {0.f, 0.f, 0.f, 0.f};
    {
      const unsigned short* ap = (wv < 2) ? h0t : h1p;
      const unsigned short* bm = (wv < 2) ? sm.W1s : sm.U1s;
      int kofs = (wv & 1) * 512;
      if (wv < 2 || t > 0) {
#pragma unroll
        for (int s8 = 0; s8 < 16; ++s8) {
          int kb = kofs + s8 * 32;
          bf16x8 av = *(const bf16x8*)(ap + lr * HID + kb + kq * 8);
          bf16x8 bv = *(const bf16x8*)&bm[(((kb >> 3) + kq) * 16 + lr) * 8];
          accB = __builtin_amdgcn_mfma_f32_16x16x32_bf16(av, bv, accB, 0, 0, 0);
        }
      }
    }
    // stage A(t+1): z0 = h0(t) @ U0
    f32x4 accA = {0.f, 0.f, 0.f, 0.f};
#pragma unroll
    for (int s8 = 0; s8 < 8; ++s8) {
      int kb = wv * 256 + s8 * 32;
      bf16x8 av = *(const bf16x8*)(h0t + lr * HID + kb + kq * 8);
      bf16x8 bv = *(const bf16x8*)&sm.U0s[(((kb >> 3) + kq) * 16 + lr) * 8];
      accA = __builtin_amdgcn_mfma_f32_16x16x32_bf16(av, bv, accA, 0, 0, 0);
    }
#pragma unroll
    for (int q = 0; q < 4; ++q) {
      sm.zB[wv][kq * 4 + q][lr] = accB[q];
      sm.zA[wv][kq * 4 + q][lr] = accA[q];
    }
    __syncthreads();

    if (wv == 0) { // layer-1 gates, time t -> stage to LDS
      int b = tid >> 2, u = tid & 3;
      int tok = sm.toks[b][t];
      float z0 = sm.b1s[0 + u]  + sm.zB[0][b][0 + u]  + sm.zB[1][b][0 + u]  + sm.zB[2][b][0 + u]  + sm.zB[3][b][0 + u];
      float z1 = sm.b1s[4 + u]  + sm.zB[0][b][4 + u]  + sm.zB[1][b][4 + u]  + sm.zB[2][b][4 + u]  + sm.zB[3][b][4 + u];
      float z2 = sm.b1s[8 + u]  + sm.zB[0][b][8 + u]  + sm.zB[1][b][8 + u]  + sm.zB[2][b][8 + u]  + sm.zB[3][b][8 + u];
      float z3 = sm.b1s[12 + u] + sm.zB[0][b][12 + u] + sm.zB[1][b][12 + u] + sm.zB[2][b][12 + u] + sm.zB[3][b][12 + u];
      float ii = 1.f / (1.f + expf(-z0));
      float ff = 1.f / (1.f + expf(-z1));
      float gg = tanhf(z2);
      float oo = 1.f / (1.f + expf(-z3));
      float cold = sm.c1[b][u], hold = sm.h1f[b][u];
      float cn = ff * cold + ii * gg;
      float hn = oo * tanhf(cn);
      if (tok == 0) { cn = cold; hn = hold; }
      sm.c1[b][u] = cn; sm.h1f[b][u] = hn;
      unsigned short hb = f2bf(hn);
      sm.h1st[b][u] = hb;
      Y1[((size_t)b * S_LEN + t) * HID + bid * 4 + u] = hb; // plain store (L2-acked)
    } else if (wv == 1) { // layer-0 gates, time t+1 -> stage to LDS
      int l = tid - 64, b = l >> 2, u = l & 3;
      int tok = sm.toks[b][t + 1];
      float z0 = xwv0 + sm.zA[0][b][0 + u]  + sm.zA[1][b][0 + u]  + sm.zA[2][b][0 + u]  + sm.zA[3][b][0 + u];
      float z1 = xwv1 + sm.zA[0][b][4 + u]  + sm.zA[1][b][4 + u]  + sm.zA[2][b][4 + u]  + sm.zA[3][b][4 + u];
      float z2 = xwv2 + sm.zA[0][b][8 + u]  + sm.zA[1][b][8 + u]  + sm.zA[2][b][8 + u]  + sm.zA[3][b][8 + u];
      float z3 = xwv3 + sm.zA[0][b][12 + u] + sm.zA[1][b][12 + u] + sm.zA[2][b][12 + u] + sm.zA[3][b][12 + u];
      float ii = 1.f / (1.f + expf(-z0));
      float ff = 1.f / (1.f + expf(-z1));
      float gg = tanhf(z2);
      float oo = 1.f / (1.f + expf(-z3));
      float cold = sm.c0[b][u], hold = sm.h0f[b][u];
      float cn = ff * cold + ii * gg;
      float hn = oo * tanhf(cn);
      if (tok == 0) { cn = cold; hn = hold; }
      sm.c0[b][u] = cn; sm.h0f[b][u] = hn;
      sm.h0st[b][u] = f2bf(hn);
    }
    __syncthreads(); // staging complete
    // wide publication: wave 0 only, 32x 8B sc1 stores (lanes 0-15: h1, 16-31: h0)
    if (tid < 32) {
      int b = tid & 15;
      unsigned long long v = *(const unsigned long long*)((tid < 16) ? &sm.h1st[b][0]
                                                                     : &sm.h0st[b][0]);
      unsigned short* dst = (tid < 16) ? (h1c + b * HID + bid * 4)
                                       : (h0n + b * HID + bid * 4);
      __hip_atomic_store((unsigned long long*)dst, v, __ATOMIC_RELAXED,
                         __HIP_MEMORY_SCOPE_AGENT);
    }
    gbar(t + 2);
  }

  // ---- epilogue: stage B(255) + layer-1 gates ----
  {
    const unsigned short* h0t = h0r + 255ull * 16384;
    const unsigned short* h1p = h1r + 254ull * 16384;
    f32x4 accB = {0.f, 0.f, 0.f, 0.f};
    const unsigned short* ap = (wv < 2) ? h0t : h1p;
    const unsigned short* bm = (wv < 2) ? sm.W1s : sm.U1s;
    int kofs = (wv & 1) * 512;
#pragma unroll
    for (int s8 = 0; s8 < 16; ++s8) {
      int kb = kofs + s8 * 32;
      bf16x8 av = *(const bf16x8*)(ap + lr * HID + kb + kq * 8);
      bf16x8 bv = *(const bf16x8*)&bm[(((kb >> 3) + kq) * 16 + lr) * 8];
      accB = __builtin_amdgcn_mfma_f32_16x16x32_bf16(av, bv, accB, 0, 0, 0);
    }
#pragma unroll
    for (int q = 0; q < 4; ++q) sm.zB[wv][kq * 4 + q][lr] = accB[q];
    __syncthreads();
    if (wv == 0) {
      int b = tid >> 2, u = tid & 3;
      int tok = sm.toks[b][255];
      float z0 = sm.b1s[0 + u]  + sm.zB[0][b][0 + u]  + sm.zB[1][b][0 + u]  + sm.zB[2][b][0 + u]  + sm.zB[3][b][0 + u];
      float z1 = sm.b1s[4 + u]  + sm.zB[0][b][4 + u]  + sm.zB[1][b][4 + u]  + sm.zB[2][b][4 + u]  + sm.zB[3][b][4 + u];
      float z2 = sm.b1s[8 + u]  + sm.zB[0][b][8 + u]  + sm.zB[1][b][8 + u]  + sm.zB[2][b][8 + u]  + sm.zB[3][b][8 + u];
      float z3 = sm.b1s[12 + u] + sm.zB[0][b][12 + u] + sm.zB[1][b][12 + u] + sm.zB[2][b][12 + u] + sm.zB[3][b][12 + u];
      float ii = 1.f / (1.f + expf(-z0));
      float ff = 1.f / (1.f + expf(-z1));
      float gg = tanhf(z2);
      float oo = 1.f / (1.f + expf(-z3));
      float cold = sm.c1[b][u], hold = sm.h1f[b][u];
      float cn = ff * cold + ii * gg;
      float hn = oo * tanhf(cn);
      if (tok == 0) { cn = cold; hn = hold; }
      sm.c1[b][u] = cn; sm.h1f[b][u] = hn;
      Y1[((size_t)b * S_LEN + 255) * HID + bid * 4 + u] = f2bf(hn);
    }
    __syncthreads();
  }

  if (tid < 64) {
    int b = tid >> 2, u = tid & 3, ug = bid * 4 + u;
    outHC[OUT_H + (size_t)b * HID + ug]         = sm.h0f[b][u];
    outHC[OUT_H + 16384 + (size_t)b * HID + ug] = sm.h1f[b][u];
    outHC[OUT_H + 32768 + (size_t)b * HID + ug] = sm.c0[b][u];
    outHC[OUT_H + 49152 + (size_t)b * HID + ug] = sm.c1[b][u];
  }
}

extern "C" void kernel_launch(void* const* d_in, const int* in_sizes, int n_in,
                              void* d_out, int out_size, void* d_ws, size_t ws_size,
                              hipStream_t stream) {
  const int*   tokens = (const int*)d_in[0];
  const float* emb = (const float*)d_in[1];
  const float* W0  = (const float*)d_in[2];
  const float* U0  = (const float*)d_in[3];
  const float* b0  = (const float*)d_in[4];
  const float* W1  = (const float*)d_in[5];
  const float* U1  = (const float*)d_in[6];
  const float* b1  = (const float*)d_in[7];
  const float* Wd  = (const float*)d_in[8];
  const float* bd  = (const float*)d_in[9];
  float* out = (float*)d_out;

  char* ws = (char*)d_ws;
  size_t off = 0;
  auto alloc = [&](size_t bytes) { char* p = ws + off; off += (bytes + 255) & ~(size_t)255; return p; };
  unsigned short* W0T = (unsigned short*)alloc(4096ull * 512 * 2);
  unsigned short* U0T = (unsigned short*)alloc(4096ull * 1024 * 2);
  unsigned short* W1T = (unsigned short*)alloc(4096ull * 1024 * 2);
  unsigned short* U1T = (unsigned short*)alloc(4096ull * 1024 * 2);
  unsigned short* WdT = (unsigned short*)alloc(32000ull * 1024 * 2);
  unsigned short* Xg  = (unsigned short*)alloc(4096ull * 512 * 2);
  unsigned short* Y1  = (unsigned short*)alloc(4096ull * 1024 * 2);
  int*   bar   = (int*)alloc(16384);            // 256 flags x 64B private lines
  float* Mpart = (float*)alloc(4096ull * 250 * 4);
  float* Spart = (float*)alloc(4096ull * 250 * 4);
  float* MS    = (float*)alloc(4096ull * 2 * 4);
  unsigned short* Lb = nullptr;
  if (ws_size >= off + 4096ull * VOCAB * 2 + 256)
    Lb = (unsigned short*)alloc(4096ull * VOCAB * 2);

  float* XW = out; // 64 MB scratch inside probs region (dead before decoder writes)
  unsigned short* h0r = (unsigned short*)((char*)d_out + 192ull * 1024 * 1024);
  unsigned short* h1r = (unsigned short*)((char*)d_out + 208ull * 1024 * 1024);

  hipMemsetAsync(bar, 0, 16384, stream); // reset flags every launch (graph-replay safe)

  hipFuncSetAttribute((const void*)k_lstm, hipFuncAttributeMaxDynamicSharedMemorySize,
                      (int)sizeof(LstmSmem));

  k_transpose_bf16<<<dim3(64, 8), 256, 0, stream>>>(W0, W0T, 512, 4096);
  k_transpose_bf16<<<dim3(64, 16), 256, 0, stream>>>(U0, U0T, 1024, 4096);
  k_transpose_bf16<<<dim3(64, 16), 256, 0, stream>>>(W1, W1T, 1024, 4096);
  k_transpose_bf16<<<dim3(64, 16), 256, 0, stream>>>(U1, U1T, 1024, 4096);
  k_transpose_bf16<<<dim3(500, 16), 256, 0, stream>>>(Wd, WdT, 1024, 32000);
  k_gather_emb<<<4096, 256, 0, stream>>>(tokens, emb, Xg);

  // XW[s*16+b][4096] = x @ W0 + b0
  k_gemm_bf16<false, false><<<dim3(32, 32), 256, 0, stream>>>(Xg, W0T, XW, nullptr, b0,
                                                              4096, 4096, 512,
                                                              nullptr, nullptr, 0);

  k_lstm<<<256, 256, sizeof(LstmSmem), stream>>>(tokens, XW, U0T, W1T, U1T, b1,
                                                 h0r, h1r, Y1, out, bar);

  // logits = Y1 @ Wd + bd, with fused softmax partials
  if (Lb) {
    k_gemm_bf16<true, true><<<dim3(250, 32), 256, 0, stream>>>(Y1, WdT, nullptr, Lb, bd,
                                                               4096, 32000, 1024,
                                                               Mpart, Spart, 250);
    k_sm_combine<<<1024, 256, 0, stream>>>(Mpart, Spart, MS, 250);
    k_sm_apply_bf16<<<4096, 256, 0, stream>>>(Lb, out, MS);
  } else {
    k_gemm_bf16<true, false><<<dim3(250, 32), 256, 0, stream>>>(Y1, WdT, out, nullptr, bd,
                                                                4096, 32000, 1024,
                                                                Mpart, Spart, 250);
    k_sm_combine<<<1024, 256, 0, stream>>>(Mpart, Spart, MS, 250);
    k_sm_apply<<<4096, 256, 0, stream>>>(out, MS);
  }
}

// Round 10
// 2150.459 us; speedup vs baseline: 1.4388x; 1.0986x over previous
//
#include <hip/hip_runtime.h>

typedef __attribute__((ext_vector_type(8))) short bf16x8;
typedef __attribute__((ext_vector_type(4))) float f32x4;

#define S_LEN 256
#define VOCAB 32000
#define EMB   512
#define HID   1024

static const size_t OUT_H = 131072000ull; // probs floats before h_stack

__device__ inline unsigned short f2bf(float f) {
  unsigned int u = __float_as_uint(f);
  u = (u + 0x7FFFu + ((u >> 16) & 1u)) >> 16;
  return (unsigned short)u;
}
__device__ inline float bf2f(unsigned short s) {
  return __uint_as_float(((unsigned int)s) << 16);
}

__device__ inline void st_h(unsigned short* p, unsigned short v) {
  __hip_atomic_store(p, v, __ATOMIC_RELAXED, __HIP_MEMORY_SCOPE_AGENT);
}

// bijective XCD chunking (m204)
__device__ inline int xcd_swz(int o, int n) {
  int q = n >> 3, r = n & 7;
  int x = o & 7, i = o >> 3;
  return (x < r ? x * (q + 1) : r * (q + 1) + (x - r) * q) + i;
}

__device__ inline void gload16(const void* g, void* lds) {
  __builtin_amdgcn_global_load_lds((const __attribute__((address_space(1))) unsigned int*)g,
                                   (__attribute__((address_space(3))) unsigned int*)lds,
                                   16, 0, 0);
}

// ---------------- transpose + f32->bf16 : dst[N][K] = bf16(src[K][N]) ----------------
__global__ __launch_bounds__(256) void k_transpose_bf16(const float* __restrict__ src,
                                                        unsigned short* __restrict__ dst,
                                                        int K, int N) {
  __shared__ float tile[64][65];
  int n0 = blockIdx.x * 64, k0 = blockIdx.y * 64;
  int tid = threadIdx.x;
#pragma unroll
  for (int i = 0; i < 16; ++i) {
    int e = tid + i * 256;
    int r = e >> 6, c = e & 63;
    tile[r][c] = src[(size_t)(k0 + r) * N + n0 + c];
  }
  __syncthreads();
#pragma unroll
  for (int i = 0; i < 16; ++i) {
    int e = tid + i * 256;
    int r = e >> 6, c = e & 63;
    dst[(size_t)(n0 + r) * K + k0 + c] = f2bf(tile[c][r]);
  }
}

// ---------------- embedding gather -> bf16, rows r = s*16 + b ----------------
__global__ __launch_bounds__(256) void k_gather_emb(const int* __restrict__ tokens,
                                                    const float* __restrict__ emb,
                                                    unsigned short* __restrict__ Xg) {
  int r = blockIdx.x;
  int s = r >> 4, b = r & 15;
  int tok = tokens[b * S_LEN + s];
  const float* src = emb + (size_t)tok * EMB;
  int k = threadIdx.x * 2;
  float2 v = *(const float2*)(src + k);
  ushort2 o; o.x = f2bf(v.x); o.y = f2bf(v.y);
  *(ushort2*)(Xg + (size_t)r * EMB + k) = o;
}

// ---------------- 128^2 bf16 GEMM (kept for XW): C f32 = A @ BT^T + bias ----------------
__global__ __launch_bounds__(256) void k_gemm128(const unsigned short* __restrict__ A,
                                                 const unsigned short* __restrict__ BT,
                                                 float* __restrict__ C,
                                                 const float* __restrict__ bias,
                                                 int M, int N, int K) {
  __shared__ unsigned short As[4096];
  __shared__ unsigned short Bs[4096];
  int tid = threadIdx.x;
  int lane = tid & 63, wv = tid >> 6;
  int wr = wv >> 1, wc = wv & 1;
  int bxs = xcd_swz(blockIdx.x, gridDim.x);
  int am0 = blockIdx.y * 128, bn0 = bxs * 128;
  f32x4 zero = {0.f, 0.f, 0.f, 0.f};
  f32x4 acc[4][4];
#pragma unroll
  for (int m = 0; m < 4; ++m)
#pragma unroll
    for (int n = 0; n < 4; ++n) acc[m][n] = zero;
  int KT = K >> 5;
  int lr = lane & 15, kq = lane >> 4;
  for (int kt = 0; kt < KT; ++kt) {
    int k0 = kt << 5;
    __syncthreads();
#pragma unroll
    for (int c = 0; c < 2; ++c) {
      int t2 = c * 256 + tid;
      int row = t2 & 127, kg = t2 >> 7;
      gload16(A + (size_t)(am0 + row) * K + k0 + kg * 8, &As[(c * 256 + wv * 64) * 8]);
    }
#pragma unroll
    for (int c = 0; c < 2; ++c) {
      int t2 = c * 256 + tid;
      int row = t2 & 127, kg = t2 >> 7;
      gload16(BT + (size_t)(bn0 + row) * K + k0 + kg * 8, &Bs[(c * 256 + wv * 64) * 8]);
    }
    __syncthreads();
    const bf16x8* Ap = (const bf16x8*)As;
    const bf16x8* Bp = (const bf16x8*)Bs;
    bf16x8 af[4], bf[4];
#pragma unroll
    for (int m = 0; m < 4; ++m) af[m] = Ap[kq * 128 + wr * 64 + m * 16 + lr];
#pragma unroll
    for (int n = 0; n < 4; ++n) bf[n] = Bp[kq * 128 + wc * 64 + n * 16 + lr];
#pragma unroll
    for (int m = 0; m < 4; ++m)
#pragma unroll
      for (int n = 0; n < 4; ++n)
        acc[m][n] = __builtin_amdgcn_mfma_f32_16x16x32_bf16(af[m], bf[n], acc[m][n], 0, 0, 0);
  }
#pragma unroll
  for (int m = 0; m < 4; ++m)
#pragma unroll
    for (int n = 0; n < 4; ++n) {
      int col = bn0 + wc * 64 + n * 16 + lr;
      float bv = bias ? bias[col] : 0.f;
#pragma unroll
      for (int q = 0; q < 4; ++q) {
        int row = am0 + wr * 64 + m * 16 + kq * 4 + q;
        C[(size_t)row * N + col] = acc[m][n][q] + bv;
      }
    }
}

// ---------------- 256^2 8-phase decoder GEMM: bf16 out + fused softmax partials ----------
// BM=BN=256, BK=64, 8 waves (2M x 4N), LDS 128KB double-buffered K-tiles (half-tile slots).
// Swizzle: LDS[row][c16] holds G[row][c16 ^ (row&7)] (pre-swizzled global src, linear dest).
__global__ __launch_bounds__(512, 2) void k_gemm256(const unsigned short* __restrict__ A,  // [M][K]
                                                    const unsigned short* __restrict__ BT, // [N][K]
                                                    unsigned short* __restrict__ Cb,       // [M][N]
                                                    const float* __restrict__ bias,
                                                    int M, int N, int K,
                                                    float* __restrict__ Mpart,
                                                    float* __restrict__ Spart,
                                                    int NT) {
  extern __shared__ unsigned short lds[]; // 2buf x 2mat x 2half x (128*64) ushort = 128KB
  int tid = threadIdx.x;
  int w = tid >> 6, lane = tid & 63;
  int wr = w >> 2, wcn = w & 3;
  int lr = lane & 15, kq = lane >> 4, sw = lr & 7;
  int bxs = xcd_swz(blockIdx.x, gridDim.x);
  int gm0 = blockIdx.y * 256, gn0 = bxs * 256;
  const int KT = K >> 6; // 64-wide K tiles (16 for K=1024)

  f32x4 acc[8][4];
#pragma unroll
  for (int m = 0; m < 8; ++m)
#pragma unroll
    for (int n = 0; n < 4; ++n) acc[m][n] = f32x4{0.f, 0.f, 0.f, 0.f};

  // stage one half-tile (128 rows x 64 cols) of matrix mat for K-tile kt
  auto stage = [&](const unsigned short* g, int grow0, int kt, int mat, int half) {
    unsigned short* sb = lds + ((((kt & 1) * 2 + mat) * 2 + half) << 13);
#pragma unroll
    for (int ld = 0; ld < 2; ++ld) {
      int j = ld * 512 + tid;
      int row = j >> 3, c16 = j & 7;
      const unsigned short* src =
          g + (size_t)(grow0 + half * 128 + row) * K + kt * 64 + ((c16 ^ (row & 7)) << 3);
      gload16(src, sb + ((ld * 512 + w * 64) << 3));
    }
  };

  // prologue: A(0) h0,h1; B(0) h0,h1; B(1) h0,h1  (12 load-instrs/wave)
  stage(A, gm0, 0, 0, 0); stage(A, gm0, 0, 0, 1);
  stage(BT, gn0, 0, 1, 0); stage(BT, gn0, 0, 1, 1);
  stage(BT, gn0, 1, 1, 0); stage(BT, gn0, 1, 1, 1);
  asm volatile("s_waitcnt vmcnt(4)" ::: "memory"); // A(0),B(0) landed; B(1) in flight
  __builtin_amdgcn_sched_barrier(0);
  __builtin_amdgcn_s_barrier();

  const int halfB = wcn >> 1;
  const int rowB0 = (wcn & 1) * 64;

  for (int i = 0; i < KT / 2; ++i) {
    int kt0 = 2 * i, kt1 = 2 * i + 1;
#pragma unroll
    for (int half = 0; half < 2; ++half) { // half 0: phases 1-4 on kt0; half 1: phases 5-8 on kt1
      int kt = half ? kt1 : kt0;
      int buf = kt & 1;
      const unsigned short* ldsA = lds + (((buf * 2 + 0) * 2 + wr) << 13);
      const unsigned short* ldsB = lds + (((buf * 2 + 1) * 2 + halfB) << 13);
      bf16x8 bf[4][2];
#pragma unroll
      for (int qd = 0; qd < 4; ++qd) {
        if (qd == 0) {
#pragma unroll
          for (int fn = 0; fn < 4; ++fn)
#pragma unroll
            for (int kk = 0; kk < 2; ++kk) {
              int r = rowB0 + fn * 16 + lr;
              int c = (kk * 4 + kq) ^ sw;
              bf[fn][kk] = *(const bf16x8*)(ldsB + r * 64 + c * 8);
            }
        }
        bf16x8 af[2][2];
#pragma unroll
        for (int m2 = 0; m2 < 2; ++m2)
#pragma unroll
          for (int kk = 0; kk < 2; ++kk) {
            int r = (qd * 2 + m2) * 16 + lr;
            int c = (kk * 4 + kq) ^ sw;
            af[m2][kk] = *(const bf16x8*)(ldsA + r * 64 + c * 8);
          }
        // staging schedule (race-free: every target slot's readers finished at an
        // earlier trailing barrier; counted vmcnt derived from issue order)
        if (half == 0) {
          if (qd == 0) { stage(A, gm0, kt0 + 1, 0, 0); stage(A, gm0, kt0 + 1, 0, 1); } // P1
          else if (qd == 1) { if (kt0 + 2 < KT) stage(BT, gn0, kt0 + 2, 1, 0); }       // P2
          else if (qd == 2) { if (kt0 + 2 < KT) stage(BT, gn0, kt0 + 2, 1, 1); }       // P3
          else {                                                                        // P4
            if (kt0 + 2 < KT) asm volatile("s_waitcnt vmcnt(4)" ::: "memory");
            else              asm volatile("s_waitcnt vmcnt(0)" ::: "memory");
          }
        } else {
          if (qd == 0)      { if (kt1 + 1 < KT) stage(A, gm0, kt1 + 1, 0, 0); }        // P5
          else if (qd == 1) { if (kt1 + 1 < KT) stage(A, gm0, kt1 + 1, 0, 1); }        // P6
          else if (qd == 2) { if (kt1 + 2 < KT) stage(BT, gn0, kt1 + 2, 1, 0); }       // P7
          else {                                                                        // P8
            if (kt1 + 2 < KT) { stage(BT, gn0, kt1 + 2, 1, 1);
                                asm volatile("s_waitcnt vmcnt(4)" ::: "memory"); }
            else              asm volatile("s_waitcnt vmcnt(0)" ::: "memory");
          }
        }
        __builtin_amdgcn_sched_barrier(0);
        __builtin_amdgcn_s_barrier();
        asm volatile("s_waitcnt lgkmcnt(0)" ::: "memory");
        __builtin_amdgcn_sched_barrier(0);
        __builtin_amdgcn_s_setprio(1);
#pragma unroll
        for (int m2 = 0; m2 < 2; ++m2)
#pragma unroll
          for (int n = 0; n < 4; ++n)
#pragma unroll
            for (int kk = 0; kk < 2; ++kk)
              acc[qd * 2 + m2][n] =
                  __builtin_amdgcn_mfma_f32_16x16x32_bf16(af[m2][kk], bf[n][kk],
                                                          acc[qd * 2 + m2][n], 0, 0, 0);
        __builtin_amdgcn_s_setprio(0);
        __builtin_amdgcn_sched_barrier(0);
        __builtin_amdgcn_s_barrier();
      }
    }
  }

  asm volatile("s_waitcnt vmcnt(0) lgkmcnt(0)" ::: "memory");
  __syncthreads();

  // epilogue: bf16 C write + fused softmax partials over the 256-col tile
  float bvc[4];
#pragma unroll
  for (int n = 0; n < 4; ++n) bvc[n] = bias[gn0 + wcn * 64 + n * 16 + lr];
#pragma unroll
  for (int fm = 0; fm < 8; ++fm)
#pragma unroll
    for (int n = 0; n < 4; ++n) {
      int col = gn0 + wcn * 64 + n * 16 + lr;
#pragma unroll
      for (int q = 0; q < 4; ++q) {
        int row = gm0 + wr * 128 + fm * 16 + kq * 4 + q;
        Cb[(size_t)row * N + col] = f2bf(acc[fm][n][q] + bvc[n]);
      }
    }
  float* redM = (float*)lds;          // [2][4][128]
  float* redS = (float*)lds + 1024;   // [2][4][128]
#pragma unroll
  for (int fm = 0; fm < 8; ++fm)
#pragma unroll
    for (int q = 0; q < 4; ++q) {
      float mx = fmaxf(fmaxf(acc[fm][0][q] + bvc[0], acc[fm][1][q] + bvc[1]),
                       fmaxf(acc[fm][2][q] + bvc[2], acc[fm][3][q] + bvc[3]));
#pragma unroll
      for (int off = 1; off < 16; off <<= 1) mx = fmaxf(mx, __shfl_xor(mx, off));
      if (lr == 0) redM[(wr * 4 + wcn) * 128 + fm * 16 + kq * 4 + q] = mx;
    }
  __syncthreads();
#pragma unroll
  for (int fm = 0; fm < 8; ++fm)
#pragma unroll
    for (int q = 0; q < 4; ++q) {
      int idx = fm * 16 + kq * 4 + q;
      float mxF = fmaxf(fmaxf(redM[(wr * 4 + 0) * 128 + idx], redM[(wr * 4 + 1) * 128 + idx]),
                        fmaxf(redM[(wr * 4 + 2) * 128 + idx], redM[(wr * 4 + 3) * 128 + idx]));
      float s = __expf(acc[fm][0][q] + bvc[0] - mxF) + __expf(acc[fm][1][q] + bvc[1] - mxF) +
                __expf(acc[fm][2][q] + bvc[2] - mxF) + __expf(acc[fm][3][q] + bvc[3] - mxF);
#pragma unroll
      for (int off = 1; off < 16; off <<= 1) s += __shfl_xor(s, off);
      if (lr == 0) redS[(wr * 4 + wcn) * 128 + idx] = s;
    }
  __syncthreads();
  if (wcn == 0 && lr == 0) {
#pragma unroll
    for (int fm = 0; fm < 8; ++fm)
#pragma unroll
      for (int q = 0; q < 4; ++q) {
        int idx = fm * 16 + kq * 4 + q;
        float mxF = fmaxf(fmaxf(redM[(wr * 4 + 0) * 128 + idx], redM[(wr * 4 + 1) * 128 + idx]),
                          fmaxf(redM[(wr * 4 + 2) * 128 + idx], redM[(wr * 4 + 3) * 128 + idx]));
        float ss = redS[(wr * 4 + 0) * 128 + idx] + redS[(wr * 4 + 1) * 128 + idx] +
                   redS[(wr * 4 + 2) * 128 + idx] + redS[(wr * 4 + 3) * 128 + idx];
        int row = gm0 + wr * 128 + idx;
        Mpart[(size_t)row * NT + bxs] = mxF;
        Spart[(size_t)row * NT + bxs] = ss;
      }
  }
}

// ---------------- softmax combine: per-row M and 1/S from tile partials ----------------
__global__ __launch_bounds__(256) void k_sm_combine(const float* __restrict__ Mp,
                                                    const float* __restrict__ Sp,
                                                    float* __restrict__ MS, int T) {
  int row = blockIdx.x * 4 + (threadIdx.x >> 6);
  int lane = threadIdx.x & 63;
  float mx = -3.4e38f;
  for (int i = lane; i < T; i += 64) mx = fmaxf(mx, Mp[(size_t)row * T + i]);
#pragma unroll
  for (int o = 32; o > 0; o >>= 1) mx = fmaxf(mx, __shfl_xor(mx, o));
  float s = 0.f;
  for (int i = lane; i < T; i += 64)
    s += Sp[(size_t)row * T + i] * __expf(Mp[(size_t)row * T + i] - mx);
#pragma unroll
  for (int o = 32; o > 0; o >>= 1) s += __shfl_xor(s, o);
  if (lane == 0) { MS[row * 2] = mx; MS[row * 2 + 1] = 1.f / s; }
}

// ---------------- softmax apply (bf16 logits -> f32 probs) ----------------
__global__ __launch_bounds__(256) void k_sm_apply_bf16(const unsigned short* __restrict__ lg,
                                                       float* __restrict__ probs,
                                                       const float* __restrict__ MS) {
  const int total = 4096 * (VOCAB / 4);
  for (int idx = blockIdx.x * 256 + threadIdx.x; idx < total; idx += gridDim.x * 256) {
    int row = idx / (VOCAB / 4);
    float M = MS[row * 2], inv = MS[row * 2 + 1];
    ushort4 v = ((const ushort4*)lg)[idx];
    float4 o;
    o.x = __expf(bf2f(v.x) - M) * inv;
    o.y = __expf(bf2f(v.y) - M) * inv;
    o.z = __expf(bf2f(v.z) - M) * inv;
    o.w = __expf(bf2f(v.w) - M) * inv;
    ((float4*)probs)[idx] = o;
  }
}

// ---------------- persistent 2-layer LSTM recurrence (R9 structure, unchanged) ----------
struct LstmSmem {
  unsigned short U0s[16384];
  unsigned short W1s[16384];
  unsigned short U1s[16384];
  float zA[4][16][16];
  float zB[4][16][16];
  float c0[16][4], h0f[16][4], c1[16][4], h1f[16][4];
  float b1s[16];
  short toks[16][256];
  unsigned short h0st[16][4], h1st[16][4];
};

__global__ __launch_bounds__(256, 1) void k_lstm(const int* __restrict__ tokens,
                                                 const float* __restrict__ XW,
                                                 const unsigned short* __restrict__ U0T,
                                                 const unsigned short* __restrict__ W1T,
                                                 const unsigned short* __restrict__ U1T,
                                                 const float* __restrict__ b1,
                                                 unsigned short* __restrict__ h0r,
                                                 unsigned short* __restrict__ h1r,
                                                 unsigned short* __restrict__ Y1,
                                                 float* outHC,
                                                 int* bar) {
  extern __shared__ char smraw[];
  LstmSmem& sm = *(LstmSmem*)smraw;
  int tid = threadIdx.x, bid = blockIdx.x;
  int lane = tid & 63, wv = tid >> 6;

  for (int idx = tid; idx < 2048; idx += 256) {
    int cidx = idx >> 7, kg = idx & 127;
    int gcol = (cidx >> 2) * 1024 + bid * 4 + (cidx & 3);
    *(uint4*)&sm.U0s[(kg * 16 + cidx) * 8] = *(const uint4*)&U0T[(size_t)gcol * 1024 + kg * 8];
    *(uint4*)&sm.W1s[(kg * 16 + cidx) * 8] = *(const uint4*)&W1T[(size_t)gcol * 1024 + kg * 8];
    *(uint4*)&sm.U1s[(kg * 16 + cidx) * 8] = *(const uint4*)&U1T[(size_t)gcol * 1024 + kg * 8];
  }
  for (int idx = tid; idx < 4096; idx += 256) {
    sm.toks[idx >> 8][idx & 255] = (short)tokens[idx];
  }
  if (tid < 64) {
    int b = tid >> 2, u = tid & 3;
    sm.c0[b][u] = 0.f; sm.h0f[b][u] = 0.f;
    sm.c1[b][u] = 0.f; sm.h1f[b][u] = 0.f;
  }
  if (tid < 16) sm.b1s[tid] = b1[(tid >> 2) * 1024 + bid * 4 + (tid & 3)];
  __syncthreads();

  int lr = lane & 15, kq = lane >> 4;

  auto gbar = [&](int gen) {
    __syncthreads();
    if (tid == 0)
      __hip_atomic_store(&bar[bid * 16], gen, __ATOMIC_RELAXED, __HIP_MEMORY_SCOPE_AGENT);
    int ok;
    do {
      int f = __hip_atomic_load(&bar[tid * 16], __ATOMIC_RELAXED, __HIP_MEMORY_SCOPE_AGENT);
      ok = (f >= gen);
    } while (!__syncthreads_and(ok));
  };

  if (wv == 1) {
    int l = tid - 64, b = l >> 2, u = l & 3;
    const float* xp = XW + (size_t)b * 4096 + bid * 4 + u;
    float z0 = xp[0], z2 = xp[2048], z3 = xp[3072];
    float ii = 1.f / (1.f + expf(-z0));
    float gg = tanhf(z2);
    float oo = 1.f / (1.f + expf(-z3));
    float cn = ii * gg;
    float hn = oo * tanhf(cn);
    if (sm.toks[b][0] == 0) { cn = 0.f; hn = 0.f; }
    sm.c0[b][u] = cn; sm.h0f[b][u] = hn;
    st_h(h0r + b * HID + bid * 4 + u, f2bf(hn));
  }
  gbar(1);

  for (int t = 0; t < 255; ++t) {
    const unsigned short* h0t = h0r + (size_t)t * 16384;
    const unsigned short* h1p = h1r + (size_t)(t > 0 ? t - 1 : 0) * 16384;
    unsigned short* h1c = h1r + (size_t)t * 16384;
    unsigned short* h0n = h0r + (size_t)(t + 1) * 16384;

    float xwv0 = 0, xwv1 = 0, xwv2 = 0, xwv3 = 0;
    if (wv == 1) {
      int l = tid - 64, b = l >> 2, u = l & 3;
      const float* xp = XW + ((size_t)(t + 1) * 16 + b) * 4096 + bid * 4 + u;
      xwv0 = xp[0]; xwv1 = xp[1024]; xwv2 = xp[2048]; xwv3 = xp[3072];
    }

    f32x4 accB = {0.f, 0.f, 0.f, 0.f};
    {
      const unsigned short* ap = (wv < 2) ? h0t : h1p;
      const unsigned short* bm = (wv < 2) ? sm.W1s : sm.U1s;
      int kofs = (wv & 1) * 512;
      if (wv < 2 || t > 0) {
#pragma unroll
        for (int s8 = 0; s8 < 16; ++s8) {
          int kb = kofs + s8 * 32;
          bf16x8 av = *(const bf16x8*)(ap + lr * HID + kb + kq * 8);
          bf16x8 bv = *(const bf16x8*)&bm[(((kb >> 3) + kq) * 16 + lr) * 8];
          accB = __builtin_amdgcn_mfma_f32_16x16x32_bf16(av, bv, accB, 0, 0, 0);
        }
      }
    }
    f32x4 accA = {0.f, 0.f, 0.f, 0.f};
#pragma unroll
    for (int s8 = 0; s8 < 8; ++s8) {
      int kb = wv * 256 + s8 * 32;
      bf16x8 av = *(const bf16x8*)(h0t + lr * HID + kb + kq * 8);
      bf16x8 bv = *(const bf16x8*)&sm.U0s[(((kb >> 3) + kq) * 16 + lr) * 8];
      accA = __builtin_amdgcn_mfma_f32_16x16x32_bf16(av, bv, accA, 0, 0, 0);
    }
#pragma unroll
    for (int q = 0; q < 4; ++q) {
      sm.zB[wv][kq * 4 + q][lr] = accB[q];
      sm.zA[wv][kq * 4 + q][lr] = accA[q];
    }
    __syncthreads();

    if (wv == 0) {
      int b = tid >> 2, u = tid & 3;
      int tok = sm.toks[b][t];
      float z0 = sm.b1s[0 + u]  + sm.zB[0][b][0 + u]  + sm.zB[1][b][0 + u]  + sm.zB[2][b][0 + u]  + sm.zB[3][b][0 + u];
      float z1 = sm.b1s[4 + u]  + sm.zB[0][b][4 + u]  + sm.zB[1][b][4 + u]  + sm.zB[2][b][4 + u]  + sm.zB[3][b][4 + u];
      float z2 = sm.b1s[8 + u]  + sm.zB[0][b][8 + u]  + sm.zB[1][b][8 + u]  + sm.zB[2][b][8 + u]  + sm.zB[3][b][8 + u];
      float z3 = sm.b1s[12 + u] + sm.zB[0][b][12 + u] + sm.zB[1][b][12 + u] + sm.zB[2][b][12 + u] + sm.zB[3][b][12 + u];
      float ii = 1.f / (1.f + expf(-z0));
      float ff = 1.f / (1.f + expf(-z1));
      float gg = tanhf(z2);
      float oo = 1.f / (1.f + expf(-z3));
      float cold = sm.c1[b][u], hold = sm.h1f[b][u];
      float cn = ff * cold + ii * gg;
      float hn = oo * tanhf(cn);
      if (tok == 0) { cn = cold; hn = hold; }
      sm.c1[b][u] = cn; sm.h1f[b][u] = hn;
      unsigned short hb = f2bf(hn);
      sm.h1st[b][u] = hb;
      Y1[((size_t)b * S_LEN + t) * HID + bid * 4 + u] = hb;
    } else if (wv == 1) {
      int l = tid - 64, b = l >> 2, u = l & 3;
      int tok = sm.toks[b][t + 1];
      float z0 = xwv0 + sm.zA[0][b][0 + u]  + sm.zA[1][b][0 + u]  + sm.zA[2][b][0 + u]  + sm.zA[3][b][0 + u];
      float z1 = xwv1 + sm.zA[0][b][4 + u]  + sm.zA[1][b][4 + u]  + sm.zA[2][b][4 + u]  + sm.zA[3][b][4 + u];
      float z2 = xwv2 + sm.zA[0][b][8 + u]  + sm.zA[1][b][8 + u]  + sm.zA[2][b][8 + u]  + sm.zA[3][b][8 + u];
      float z3 = xwv3 + sm.zA[0][b][12 + u] + sm.zA[1][b][12 + u] + sm.zA[2][b][12 + u] + sm.zA[3][b][12 + u];
      float ii = 1.f / (1.f + expf(-z0));
      float ff = 1.f / (1.f + expf(-z1));
      float gg = tanhf(z2);
      float oo = 1.f / (1.f + expf(-z3));
      float cold = sm.c0[b][u], hold = sm.h0f[b][u];
      float cn = ff * cold + ii * gg;
      float hn = oo * tanhf(cn);
      if (tok == 0) { cn = cold; hn = hold; }
      sm.c0[b][u] = cn; sm.h0f[b][u] = hn;
      sm.h0st[b][u] = f2bf(hn);
    }
    __syncthreads();
    if (tid < 32) {
      int b = tid & 15;
      unsigned long long v = *(const unsigned long long*)((tid < 16) ? &sm.h1st[b][0]
                                                                     : &sm.h0st[b][0]);
      unsigned short* dst = (tid < 16) ? (h1c + b * HID + bid * 4)
                                       : (h0n + b * HID + bid * 4);
      __hip_atomic_store((unsigned long long*)dst, v, __ATOMIC_RELAXED,
                         __HIP_MEMORY_SCOPE_AGENT);
    }
    gbar(t + 2);
  }

  {
    const unsigned short* h0t = h0r + 255ull * 16384;
    const unsigned short* h1p = h1r + 254ull * 16384;
    f32x4 accB = {0.f, 0.f, 0.f, 0.f};
    const unsigned short* ap = (wv < 2) ? h0t : h1p;
    const unsigned short* bm = (wv < 2) ? sm.W1s : sm.U1s;
    int kofs = (wv & 1) * 512;
#pragma unroll
    for (int s8 = 0; s8 < 16; ++s8) {
      int kb = kofs + s8 * 32;
      bf16x8 av = *(const bf16x8*)(ap + lr * HID + kb + kq * 8);
      bf16x8 bv = *(const bf16x8*)&bm[(((kb >> 3) + kq) * 16 + lr) * 8];
      accB = __builtin_amdgcn_mfma_f32_16x16x32_bf16(av, bv, accB, 0, 0, 0);
    }
#pragma unroll
    for (int q = 0; q < 4; ++q) sm.zB[wv][kq * 4 + q][lr] = accB[q];
    __syncthreads();
    if (wv == 0) {
      int b = tid >> 2, u = tid & 3;
      int tok = sm.toks[b][255];
      float z0 = sm.b1s[0 + u]  + sm.zB[0][b][0 + u]  + sm.zB[1][b][0 + u]  + sm.zB[2][b][0 + u]  + sm.zB[3][b][0 + u];
      float z1 = sm.b1s[4 + u]  + sm.zB[0][b][4 + u]  + sm.zB[1][b][4 + u]  + sm.zB[2][b][4 + u]  + sm.zB[3][b][4 + u];
      float z2 = sm.b1s[8 + u]  + sm.zB[0][b][8 + u]  + sm.zB[1][b][8 + u]  + sm.zB[2][b][8 + u]  + sm.zB[3][b][8 + u];
      float z3 = sm.b1s[12 + u] + sm.zB[0][b][12 + u] + sm.zB[1][b][12 + u] + sm.zB[2][b][12 + u] + sm.zB[3][b][12 + u];
      float ii = 1.f / (1.f + expf(-z0));
      float ff = 1.f / (1.f + expf(-z1));
      float gg = tanhf(z2);
      float oo = 1.f / (1.f + expf(-z3));
      float cold = sm.c1[b][u], hold = sm.h1f[b][u];
      float cn = ff * cold + ii * gg;
      float hn = oo * tanhf(cn);
      if (tok == 0) { cn = cold; hn = hold; }
      sm.c1[b][u] = cn; sm.h1f[b][u] = hn;
      Y1[((size_t)b * S_LEN + 255) * HID + bid * 4 + u] = f2bf(hn);
    }
    __syncthreads();
  }

  if (tid < 64) {
    int b = tid >> 2, u = tid & 3, ug = bid * 4 + u;
    outHC[OUT_H + (size_t)b * HID + ug]         = sm.h0f[b][u];
    outHC[OUT_H + 16384 + (size_t)b * HID + ug] = sm.h1f[b][u];
    outHC[OUT_H + 32768 + (size_t)b * HID + ug] = sm.c0[b][u];
    outHC[OUT_H + 49152 + (size_t)b * HID + ug] = sm.c1[b][u];
  }
}

extern "C" void kernel_launch(void* const* d_in, const int* in_sizes, int n_in,
                              void* d_out, int out_size, void* d_ws, size_t ws_size,
                              hipStream_t stream) {
  const int*   tokens = (const int*)d_in[0];
  const float* emb = (const float*)d_in[1];
  const float* W0  = (const float*)d_in[2];
  const float* U0  = (const float*)d_in[3];
  const float* b0  = (const float*)d_in[4];
  const float* W1  = (const float*)d_in[5];
  const float* U1  = (const float*)d_in[6];
  const float* b1  = (const float*)d_in[7];
  const float* Wd  = (const float*)d_in[8];
  const float* bd  = (const float*)d_in[9];
  float* out = (float*)d_out;

  char* ws = (char*)d_ws;
  size_t off = 0;
  auto alloc = [&](size_t bytes) { char* p = ws + off; off += (bytes + 255) & ~(size_t)255; return p; };
  unsigned short* W0T = (unsigned short*)alloc(4096ull * 512 * 2);
  unsigned short* U0T = (unsigned short*)alloc(4096ull * 1024 * 2);
  unsigned short* W1T = (unsigned short*)alloc(4096ull * 1024 * 2);
  unsigned short* U1T = (unsigned short*)alloc(4096ull * 1024 * 2);
  unsigned short* WdT = (unsigned short*)alloc(32000ull * 1024 * 2);
  unsigned short* Xg  = (unsigned short*)alloc(4096ull * 512 * 2);
  unsigned short* Y1  = (unsigned short*)alloc(4096ull * 1024 * 2);
  int*   bar   = (int*)alloc(16384);
  float* Mpart = (float*)alloc(4096ull * 125 * 4);
  float* Spart = (float*)alloc(4096ull * 125 * 4);
  float* MS    = (float*)alloc(4096ull * 2 * 4);
  unsigned short* Lb = (unsigned short*)alloc(4096ull * VOCAB * 2);

  float* XW = out; // 64 MB scratch inside probs region (dead before decoder writes)
  unsigned short* h0r = (unsigned short*)((char*)d_out + 192ull * 1024 * 1024);
  unsigned short* h1r = (unsigned short*)((char*)d_out + 208ull * 1024 * 1024);

  hipMemsetAsync(bar, 0, 16384, stream);

  hipFuncSetAttribute((const void*)k_lstm, hipFuncAttributeMaxDynamicSharedMemorySize,
                      (int)sizeof(LstmSmem));
  hipFuncSetAttribute((const void*)k_gemm256, hipFuncAttributeMaxDynamicSharedMemorySize,
                      131072);

  k_transpose_bf16<<<dim3(64, 8), 256, 0, stream>>>(W0, W0T, 512, 4096);
  k_transpose_bf16<<<dim3(64, 16), 256, 0, stream>>>(U0, U0T, 1024, 4096);
  k_transpose_bf16<<<dim3(64, 16), 256, 0, stream>>>(W1, W1T, 1024, 4096);
  k_transpose_bf16<<<dim3(64, 16), 256, 0, stream>>>(U1, U1T, 1024, 4096);
  k_transpose_bf16<<<dim3(500, 16), 256, 0, stream>>>(Wd, WdT, 1024, 32000);
  k_gather_emb<<<4096, 256, 0, stream>>>(tokens, emb, Xg);

  // XW[s*16+b][4096] = x @ W0 + b0  (128^2 kernel)
  k_gemm128<<<dim3(32, 32), 256, 0, stream>>>(Xg, W0T, XW, b0, 4096, 4096, 512);

  k_lstm<<<256, 256, sizeof(LstmSmem), stream>>>(tokens, XW, U0T, W1T, U1T, b1,
                                                 h0r, h1r, Y1, out, bar);

  // logits = Y1 @ Wd + bd  (256^2 8-phase kernel, bf16 out + softmax partials)
  k_gemm256<<<dim3(125, 16), 512, 131072, stream>>>(Y1, WdT, Lb, bd, 4096, 32000, 1024,
                                                    Mpart, Spart, 125);
  k_sm_combine<<<1024, 256, 0, stream>>>(Mpart, Spart, MS, 125);
  k_sm_apply_bf16<<<4096, 256, 0, stream>>>(Lb, out, MS);
}

// Round 11
// 2109.319 us; speedup vs baseline: 1.4669x; 1.0195x over previous
//
#include <hip/hip_runtime.h>

typedef __attribute__((ext_vector_type(8))) short bf16x8;
typedef __attribute__((ext_vector_type(4))) float f32x4;

#define S_LEN 256
#define VOCAB 32000
#define EMB   512
#define HID   1024

static const size_t OUT_H = 131072000ull; // probs floats before h_stack

__device__ inline unsigned short f2bf(float f) {
  unsigned int u = __float_as_uint(f);
  u = (u + 0x7FFFu + ((u >> 16) & 1u)) >> 16;
  return (unsigned short)u;
}
__device__ inline float bf2f(unsigned short s) {
  return __uint_as_float(((unsigned int)s) << 16);
}

__device__ inline void st_h(unsigned short* p, unsigned short v) {
  __hip_atomic_store(p, v, __ATOMIC_RELAXED, __HIP_MEMORY_SCOPE_AGENT);
}

// bijective XCD chunking (m204)
__device__ inline int xcd_swz(int o, int n) {
  int q = n >> 3, r = n & 7;
  int x = o & 7, i = o >> 3;
  return (x < r ? x * (q + 1) : r * (q + 1) + (x - r) * q) + i;
}

__device__ inline void gload16(const void* g, void* lds) {
  __builtin_amdgcn_global_load_lds((const __attribute__((address_space(1))) unsigned int*)g,
                                   (__attribute__((address_space(3))) unsigned int*)lds,
                                   16, 0, 0);
}

// ---------------- transpose + f32->bf16 : dst[N][K] = bf16(src[K][N]) ----------------
__global__ __launch_bounds__(256) void k_transpose_bf16(const float* __restrict__ src,
                                                        unsigned short* __restrict__ dst,
                                                        int K, int N) {
  __shared__ float tile[64][65];
  int n0 = blockIdx.x * 64, k0 = blockIdx.y * 64;
  int tid = threadIdx.x;
#pragma unroll
  for (int i = 0; i < 16; ++i) {
    int e = tid + i * 256;
    int r = e >> 6, c = e & 63;
    tile[r][c] = src[(size_t)(k0 + r) * N + n0 + c];
  }
  __syncthreads();
#pragma unroll
  for (int i = 0; i < 16; ++i) {
    int e = tid + i * 256;
    int r = e >> 6, c = e & 63;
    dst[(size_t)(n0 + r) * K + k0 + c] = f2bf(tile[c][r]);
  }
}

// fused variant: 3 matrices of identical K=1024 -> N=4096 shape, picked by blockIdx.z
__global__ __launch_bounds__(256) void k_transpose3(const float* __restrict__ s0,
                                                    const float* __restrict__ s1,
                                                    const float* __restrict__ s2,
                                                    unsigned short* __restrict__ d0,
                                                    unsigned short* __restrict__ d1,
                                                    unsigned short* __restrict__ d2) {
  __shared__ float tile[64][65];
  const float* src = (blockIdx.z == 0) ? s0 : (blockIdx.z == 1) ? s1 : s2;
  unsigned short* dst = (blockIdx.z == 0) ? d0 : (blockIdx.z == 1) ? d1 : d2;
  const int K = 1024, N = 4096;
  int n0 = blockIdx.x * 64, k0 = blockIdx.y * 64;
  int tid = threadIdx.x;
#pragma unroll
  for (int i = 0; i < 16; ++i) {
    int e = tid + i * 256;
    int r = e >> 6, c = e & 63;
    tile[r][c] = src[(size_t)(k0 + r) * N + n0 + c];
  }
  __syncthreads();
#pragma unroll
  for (int i = 0; i < 16; ++i) {
    int e = tid + i * 256;
    int r = e >> 6, c = e & 63;
    dst[(size_t)(n0 + r) * K + k0 + c] = f2bf(tile[c][r]);
  }
}

// ---------------- embedding gather -> bf16, rows r = s*16 + b ----------------
__global__ __launch_bounds__(256) void k_gather_emb(const int* __restrict__ tokens,
                                                    const float* __restrict__ emb,
                                                    unsigned short* __restrict__ Xg) {
  int r = blockIdx.x;
  int s = r >> 4, b = r & 15;
  int tok = tokens[b * S_LEN + s];
  const float* src = emb + (size_t)tok * EMB;
  int k = threadIdx.x * 2;
  float2 v = *(const float2*)(src + k);
  ushort2 o; o.x = f2bf(v.x); o.y = f2bf(v.y);
  *(ushort2*)(Xg + (size_t)r * EMB + k) = o;
}

// ---------------- 256^2 8-phase GEMM ----------------------------------------------------
// BM=BN=256, BK=64, 8 waves (2M x 4N), LDS 128KB double-buffered K-tiles (half-tile slots).
// Swizzle: LDS[row][c16] holds G[row][c16 ^ (row&7)] (pre-swizzled global src, linear dest).
// BF16OUT: bf16 C; SMPART: fused per-(row,tile) softmax partials; REMAP: A-row r=(t*16+b)
// maps to output row b*256+t (decoder consumes h1r t-major, emits logits (b,s)-major).
template <bool BF16OUT, bool SMPART, bool REMAP>
__global__ __launch_bounds__(512, 2) void k_gemm256(const unsigned short* __restrict__ A,  // [M][K]
                                                    const unsigned short* __restrict__ BT, // [N][K]
                                                    float* __restrict__ Cf,
                                                    unsigned short* __restrict__ Cb,
                                                    const float* __restrict__ bias,
                                                    int M, int N, int K,
                                                    float* __restrict__ Mpart,
                                                    float* __restrict__ Spart,
                                                    int NT) {
  extern __shared__ unsigned short lds[]; // 2buf x 2mat x 2half x (128*64) ushort = 128KB
  int tid = threadIdx.x;
  int w = tid >> 6, lane = tid & 63;
  int wr = w >> 2, wcn = w & 3;
  int lr = lane & 15, kq = lane >> 4, sw = lr & 7;
  int bxs = xcd_swz(blockIdx.x, gridDim.x);
  int gm0 = blockIdx.y * 256, gn0 = bxs * 256;
  const int KT = K >> 6;

  f32x4 acc[8][4];
#pragma unroll
  for (int m = 0; m < 8; ++m)
#pragma unroll
    for (int n = 0; n < 4; ++n) acc[m][n] = f32x4{0.f, 0.f, 0.f, 0.f};

  auto stage = [&](const unsigned short* g, int grow0, int kt, int mat, int half) {
    unsigned short* sb = lds + ((((kt & 1) * 2 + mat) * 2 + half) << 13);
#pragma unroll
    for (int ld = 0; ld < 2; ++ld) {
      int j = ld * 512 + tid;
      int row = j >> 3, c16 = j & 7;
      const unsigned short* src =
          g + (size_t)(grow0 + half * 128 + row) * K + kt * 64 + ((c16 ^ (row & 7)) << 3);
      gload16(src, sb + ((ld * 512 + w * 64) << 3));
    }
  };

  stage(A, gm0, 0, 0, 0); stage(A, gm0, 0, 0, 1);
  stage(BT, gn0, 0, 1, 0); stage(BT, gn0, 0, 1, 1);
  stage(BT, gn0, 1, 1, 0); stage(BT, gn0, 1, 1, 1);
  asm volatile("s_waitcnt vmcnt(4)" ::: "memory");
  __builtin_amdgcn_sched_barrier(0);
  __builtin_amdgcn_s_barrier();

  const int halfB = wcn >> 1;
  const int rowB0 = (wcn & 1) * 64;

  for (int i = 0; i < KT / 2; ++i) {
    int kt0 = 2 * i, kt1 = 2 * i + 1;
#pragma unroll
    for (int half = 0; half < 2; ++half) {
      int kt = half ? kt1 : kt0;
      int buf = kt & 1;
      const unsigned short* ldsA = lds + (((buf * 2 + 0) * 2 + wr) << 13);
      const unsigned short* ldsB = lds + (((buf * 2 + 1) * 2 + halfB) << 13);
      bf16x8 bf[4][2];
#pragma unroll
      for (int qd = 0; qd < 4; ++qd) {
        if (qd == 0) {
#pragma unroll
          for (int fn = 0; fn < 4; ++fn)
#pragma unroll
            for (int kk = 0; kk < 2; ++kk) {
              int r = rowB0 + fn * 16 + lr;
              int c = (kk * 4 + kq) ^ sw;
              bf[fn][kk] = *(const bf16x8*)(ldsB + r * 64 + c * 8);
            }
        }
        bf16x8 af[2][2];
#pragma unroll
        for (int m2 = 0; m2 < 2; ++m2)
#pragma unroll
          for (int kk = 0; kk < 2; ++kk) {
            int r = (qd * 2 + m2) * 16 + lr;
            int c = (kk * 4 + kq) ^ sw;
            af[m2][kk] = *(const bf16x8*)(ldsA + r * 64 + c * 8);
          }
        if (half == 0) {
          if (qd == 0) { stage(A, gm0, kt0 + 1, 0, 0); stage(A, gm0, kt0 + 1, 0, 1); }
          else if (qd == 1) { if (kt0 + 2 < KT) stage(BT, gn0, kt0 + 2, 1, 0); }
          else if (qd == 2) { if (kt0 + 2 < KT) stage(BT, gn0, kt0 + 2, 1, 1); }
          else {
            if (kt0 + 2 < KT) asm volatile("s_waitcnt vmcnt(4)" ::: "memory");
            else              asm volatile("s_waitcnt vmcnt(0)" ::: "memory");
          }
        } else {
          if (qd == 0)      { if (kt1 + 1 < KT) stage(A, gm0, kt1 + 1, 0, 0); }
          else if (qd == 1) { if (kt1 + 1 < KT) stage(A, gm0, kt1 + 1, 0, 1); }
          else if (qd == 2) { if (kt1 + 2 < KT) stage(BT, gn0, kt1 + 2, 1, 0); }
          else {
            if (kt1 + 2 < KT) { stage(BT, gn0, kt1 + 2, 1, 1);
                                asm volatile("s_waitcnt vmcnt(4)" ::: "memory"); }
            else              asm volatile("s_waitcnt vmcnt(0)" ::: "memory");
          }
        }
        __builtin_amdgcn_sched_barrier(0);
        __builtin_amdgcn_s_barrier();
        asm volatile("s_waitcnt lgkmcnt(0)" ::: "memory");
        __builtin_amdgcn_sched_barrier(0);
        __builtin_amdgcn_s_setprio(1);
#pragma unroll
        for (int m2 = 0; m2 < 2; ++m2)
#pragma unroll
          for (int n = 0; n < 4; ++n)
#pragma unroll
            for (int kk = 0; kk < 2; ++kk)
              acc[qd * 2 + m2][n] =
                  __builtin_amdgcn_mfma_f32_16x16x32_bf16(af[m2][kk], bf[n][kk],
                                                          acc[qd * 2 + m2][n], 0, 0, 0);
        __builtin_amdgcn_s_setprio(0);
        __builtin_amdgcn_sched_barrier(0);
        __builtin_amdgcn_s_barrier();
      }
    }
  }

  asm volatile("s_waitcnt vmcnt(0) lgkmcnt(0)" ::: "memory");
  __syncthreads();

  float bvc[4];
#pragma unroll
  for (int n = 0; n < 4; ++n) bvc[n] = bias[gn0 + wcn * 64 + n * 16 + lr];
#pragma unroll
  for (int fm = 0; fm < 8; ++fm)
#pragma unroll
    for (int n = 0; n < 4; ++n) {
      int col = gn0 + wcn * 64 + n * 16 + lr;
#pragma unroll
      for (int q = 0; q < 4; ++q) {
        int r = gm0 + wr * 128 + fm * 16 + kq * 4 + q;
        int row = REMAP ? (((r & 15) << 8) | (r >> 4)) : r;
        if constexpr (BF16OUT)
          Cb[(size_t)row * N + col] = f2bf(acc[fm][n][q] + bvc[n]);
        else
          Cf[(size_t)row * N + col] = acc[fm][n][q] + bvc[n];
      }
    }
  if constexpr (SMPART) {
    float* redM = (float*)lds;          // [2][4][128]
    float* redS = (float*)lds + 1024;   // [2][4][128]
#pragma unroll
    for (int fm = 0; fm < 8; ++fm)
#pragma unroll
      for (int q = 0; q < 4; ++q) {
        float mx = fmaxf(fmaxf(acc[fm][0][q] + bvc[0], acc[fm][1][q] + bvc[1]),
                         fmaxf(acc[fm][2][q] + bvc[2], acc[fm][3][q] + bvc[3]));
#pragma unroll
        for (int off = 1; off < 16; off <<= 1) mx = fmaxf(mx, __shfl_xor(mx, off));
        if (lr == 0) redM[(wr * 4 + wcn) * 128 + fm * 16 + kq * 4 + q] = mx;
      }
    __syncthreads();
#pragma unroll
    for (int fm = 0; fm < 8; ++fm)
#pragma unroll
      for (int q = 0; q < 4; ++q) {
        int idx = fm * 16 + kq * 4 + q;
        float mxF = fmaxf(fmaxf(redM[(wr * 4 + 0) * 128 + idx], redM[(wr * 4 + 1) * 128 + idx]),
                          fmaxf(redM[(wr * 4 + 2) * 128 + idx], redM[(wr * 4 + 3) * 128 + idx]));
        float s = __expf(acc[fm][0][q] + bvc[0] - mxF) + __expf(acc[fm][1][q] + bvc[1] - mxF) +
                  __expf(acc[fm][2][q] + bvc[2] - mxF) + __expf(acc[fm][3][q] + bvc[3] - mxF);
#pragma unroll
        for (int off = 1; off < 16; off <<= 1) s += __shfl_xor(s, off);
        if (lr == 0) redS[(wr * 4 + wcn) * 128 + idx] = s;
      }
    __syncthreads();
    if (wcn == 0 && lr == 0) {
#pragma unroll
      for (int fm = 0; fm < 8; ++fm)
#pragma unroll
        for (int q = 0; q < 4; ++q) {
          int idx = fm * 16 + kq * 4 + q;
          float mxF = fmaxf(fmaxf(redM[(wr * 4 + 0) * 128 + idx], redM[(wr * 4 + 1) * 128 + idx]),
                            fmaxf(redM[(wr * 4 + 2) * 128 + idx], redM[(wr * 4 + 3) * 128 + idx]));
          float ss = redS[(wr * 4 + 0) * 128 + idx] + redS[(wr * 4 + 1) * 128 + idx] +
                     redS[(wr * 4 + 2) * 128 + idx] + redS[(wr * 4 + 3) * 128 + idx];
          int r = gm0 + wr * 128 + idx;
          int row = REMAP ? (((r & 15) << 8) | (r >> 4)) : r;
          Mpart[(size_t)row * NT + bxs] = mxF;
          Spart[(size_t)row * NT + bxs] = ss;
        }
    }
  }
}

// ---------------- softmax combine: per-row M and 1/S from tile partials ----------------
__global__ __launch_bounds__(256) void k_sm_combine(const float* __restrict__ Mp,
                                                    const float* __restrict__ Sp,
                                                    float* __restrict__ MS, int T) {
  int row = blockIdx.x * 4 + (threadIdx.x >> 6);
  int lane = threadIdx.x & 63;
  float mx = -3.4e38f;
  for (int i = lane; i < T; i += 64) mx = fmaxf(mx, Mp[(size_t)row * T + i]);
#pragma unroll
  for (int o = 32; o > 0; o >>= 1) mx = fmaxf(mx, __shfl_xor(mx, o));
  float s = 0.f;
  for (int i = lane; i < T; i += 64)
    s += Sp[(size_t)row * T + i] * __expf(Mp[(size_t)row * T + i] - mx);
#pragma unroll
  for (int o = 32; o > 0; o >>= 1) s += __shfl_xor(s, o);
  if (lane == 0) { MS[row * 2] = mx; MS[row * 2 + 1] = 1.f / s; }
}

// ---------------- softmax apply (bf16 logits -> f32 probs) ----------------
__global__ __launch_bounds__(256) void k_sm_apply_bf16(const unsigned short* __restrict__ lg,
                                                       float* __restrict__ probs,
                                                       const float* __restrict__ MS) {
  const int total = 4096 * (VOCAB / 4);
  for (int idx = blockIdx.x * 256 + threadIdx.x; idx < total; idx += gridDim.x * 256) {
    int row = idx / (VOCAB / 4);
    float M = MS[row * 2], inv = MS[row * 2 + 1];
    ushort4 v = ((const ushort4*)lg)[idx];
    float4 o;
    o.x = __expf(bf2f(v.x) - M) * inv;
    o.y = __expf(bf2f(v.y) - M) * inv;
    o.z = __expf(bf2f(v.z) - M) * inv;
    o.w = __expf(bf2f(v.w) - M) * inv;
    ((float4*)probs)[idx] = o;
  }
}

// ---------------- persistent 2-layer LSTM recurrence ----------------
struct LstmSmem {
  unsigned short U0s[16384];
  unsigned short W1s[16384];
  unsigned short U1s[16384];
  float zA[4][16][16];
  float zB[4][16][16];
  float c0[16][4], h0f[16][4], c1[16][4], h1f[16][4];
  float b1s[16];
  short toks[16][256];
  unsigned short h0st[16][4], h1st[16][4];
};

__global__ __launch_bounds__(256, 1) void k_lstm(const int* __restrict__ tokens,
                                                 const float* __restrict__ XW,
                                                 const unsigned short* __restrict__ U0T,
                                                 const unsigned short* __restrict__ W1T,
                                                 const unsigned short* __restrict__ U1T,
                                                 const float* __restrict__ b1,
                                                 unsigned short* __restrict__ h0r,
                                                 unsigned short* __restrict__ h1r,
                                                 float* outHC,
                                                 int* bar) {
  extern __shared__ char smraw[];
  LstmSmem& sm = *(LstmSmem*)smraw;
  int tid = threadIdx.x, bid = blockIdx.x;
  int lane = tid & 63, wv = tid >> 6;

  for (int idx = tid; idx < 2048; idx += 256) {
    int cidx = idx >> 7, kg = idx & 127;
    int gcol = (cidx >> 2) * 1024 + bid * 4 + (cidx & 3);
    *(uint4*)&sm.U0s[(kg * 16 + cidx) * 8] = *(const uint4*)&U0T[(size_t)gcol * 1024 + kg * 8];
    *(uint4*)&sm.W1s[(kg * 16 + cidx) * 8] = *(const uint4*)&W1T[(size_t)gcol * 1024 + kg * 8];
    *(uint4*)&sm.U1s[(kg * 16 + cidx) * 8] = *(const uint4*)&U1T[(size_t)gcol * 1024 + kg * 8];
  }
  for (int idx = tid; idx < 4096; idx += 256) {
    sm.toks[idx >> 8][idx & 255] = (short)tokens[idx];
  }
  if (tid < 64) {
    int b = tid >> 2, u = tid & 3;
    sm.c0[b][u] = 0.f; sm.h0f[b][u] = 0.f;
    sm.c1[b][u] = 0.f; sm.h1f[b][u] = 0.f;
  }
  if (tid < 16) sm.b1s[tid] = b1[(tid >> 2) * 1024 + bid * 4 + (tid & 3)];
  __syncthreads();

  int lr = lane & 15, kq = lane >> 4;

  auto gbar = [&](int gen) {
    __syncthreads();
    if (tid == 0)
      __hip_atomic_store(&bar[bid * 16], gen, __ATOMIC_RELAXED, __HIP_MEMORY_SCOPE_AGENT);
    int ok;
    do {
      int f = __hip_atomic_load(&bar[tid * 16], __ATOMIC_RELAXED, __HIP_MEMORY_SCOPE_AGENT);
      ok = (f >= gen);
    } while (!__syncthreads_and(ok));
  };

  if (wv == 1) {
    int l = tid - 64, b = l >> 2, u = l & 3;
    const float* xp = XW + (size_t)b * 4096 + bid * 4 + u;
    float z0 = xp[0], z2 = xp[2048], z3 = xp[3072];
    float ii = 1.f / (1.f + expf(-z0));
    float gg = tanhf(z2);
    float oo = 1.f / (1.f + expf(-z3));
    float cn = ii * gg;
    float hn = oo * tanhf(cn);
    if (sm.toks[b][0] == 0) { cn = 0.f; hn = 0.f; }
    sm.c0[b][u] = cn; sm.h0f[b][u] = hn;
    st_h(h0r + b * HID + bid * 4 + u, f2bf(hn));
  }
  gbar(1);

  for (int t = 0; t < 255; ++t) {
    const unsigned short* h0t = h0r + (size_t)t * 16384;
    const unsigned short* h1p = h1r + (size_t)(t > 0 ? t - 1 : 0) * 16384;
    unsigned short* h1c = h1r + (size_t)t * 16384;
    unsigned short* h0n = h0r + (size_t)(t + 1) * 16384;

    float xwv0 = 0, xwv1 = 0, xwv2 = 0, xwv3 = 0;
    if (wv == 1) {
      int l = tid - 64, b = l >> 2, u = l & 3;
      const float* xp = XW + ((size_t)(t + 1) * 16 + b) * 4096 + bid * 4 + u;
      xwv0 = xp[0]; xwv1 = xp[1024]; xwv2 = xp[2048]; xwv3 = xp[3072];
    }

    f32x4 accB = {0.f, 0.f, 0.f, 0.f};
    {
      const unsigned short* ap = (wv < 2) ? h0t : h1p;
      const unsigned short* bm = (wv < 2) ? sm.W1s : sm.U1s;
      int kofs = (wv & 1) * 512;
      if (wv < 2 || t > 0) {
#pragma unroll
        for (int s8 = 0; s8 < 16; ++s8) {
          int kb = kofs + s8 * 32;
          bf16x8 av = *(const bf16x8*)(ap + lr * HID + kb + kq * 8);
          bf16x8 bv = *(const bf16x8*)&bm[(((kb >> 3) + kq) * 16 + lr) * 8];
          accB = __builtin_amdgcn_mfma_f32_16x16x32_bf16(av, bv, accB, 0, 0, 0);
        }
      }
    }
    f32x4 accA = {0.f, 0.f, 0.f, 0.f};
#pragma unroll
    for (int s8 = 0; s8 < 8; ++s8) {
      int kb = wv * 256 + s8 * 32;
      bf16x8 av = *(const bf16x8*)(h0t + lr * HID + kb + kq * 8);
      bf16x8 bv = *(const bf16x8*)&sm.U0s[(((kb >> 3) + kq) * 16 + lr) * 8];
      accA = __builtin_amdgcn_mfma_f32_16x16x32_bf16(av, bv, accA, 0, 0, 0);
    }
#pragma unroll
    for (int q = 0; q < 4; ++q) {
      sm.zB[wv][kq * 4 + q][lr] = accB[q];
      sm.zA[wv][kq * 4 + q][lr] = accA[q];
    }
    __syncthreads();

    if (wv == 0) {
      int b = tid >> 2, u = tid & 3;
      int tok = sm.toks[b][t];
      float z0 = sm.b1s[0 + u]  + sm.zB[0][b][0 + u]  + sm.zB[1][b][0 + u]  + sm.zB[2][b][0 + u]  + sm.zB[3][b][0 + u];
      float z1 = sm.b1s[4 + u]  + sm.zB[0][b][4 + u]  + sm.zB[1][b][4 + u]  + sm.zB[2][b][4 + u]  + sm.zB[3][b][4 + u];
      float z2 = sm.b1s[8 + u]  + sm.zB[0][b][8 + u]  + sm.zB[1][b][8 + u]  + sm.zB[2][b][8 + u]  + sm.zB[3][b][8 + u];
      float z3 = sm.b1s[12 + u] + sm.zB[0][b][12 + u] + sm.zB[1][b][12 + u] + sm.zB[2][b][12 + u] + sm.zB[3][b][12 + u];
      float ii = 1.f / (1.f + expf(-z0));
      float ff = 1.f / (1.f + expf(-z1));
      float gg = tanhf(z2);
      float oo = 1.f / (1.f + expf(-z3));
      float cold = sm.c1[b][u], hold = sm.h1f[b][u];
      float cn = ff * cold + ii * gg;
      float hn = oo * tanhf(cn);
      if (tok == 0) { cn = cold; hn = hold; }
      sm.c1[b][u] = cn; sm.h1f[b][u] = hn;
      sm.h1st[b][u] = f2bf(hn);
    } else if (wv == 1) {
      int l = tid - 64, b = l >> 2, u = l & 3;
      int tok = sm.toks[b][t + 1];
      float z0 = xwv0 + sm.zA[0][b][0 + u]  + sm.zA[1][b][0 + u]  + sm.zA[2][b][0 + u]  + sm.zA[3][b][0 + u];
      float z1 = xwv1 + sm.zA[0][b][4 + u]  + sm.zA[1][b][4 + u]  + sm.zA[2][b][4 + u]  + sm.zA[3][b][4 + u];
      float z2 = xwv2 + sm.zA[0][b][8 + u]  + sm.zA[1][b][8 + u]  + sm.zA[2][b][8 + u]  + sm.zA[3][b][8 + u];
      float z3 = xwv3 + sm.zA[0][b][12 + u] + sm.zA[1][b][12 + u] + sm.zA[2][b][12 + u] + sm.zA[3][b][12 + u];
      float ii = 1.f / (1.f + expf(-z0));
      float ff = 1.f / (1.f + expf(-z1));
      float gg = tanhf(z2);
      float oo = 1.f / (1.f + expf(-z3));
      float cold = sm.c0[b][u], hold = sm.h0f[b][u];
      float cn = ff * cold + ii * gg;
      float hn = oo * tanhf(cn);
      if (tok == 0) { cn = cold; hn = hold; }
      sm.c0[b][u] = cn; sm.h0f[b][u] = hn;
      sm.h0st[b][u] = f2bf(hn);
    }
    __syncthreads();
    if (tid < 32) {
      int b = tid & 15;
      unsigned long long v = *(const unsigned long long*)((tid < 16) ? &sm.h1st[b][0]
                                                                     : &sm.h0st[b][0]);
      unsigned short* dst = (tid < 16) ? (h1c + b * HID + bid * 4)
                                       : (h0n + b * HID + bid * 4);
      __hip_atomic_store((unsigned long long*)dst, v, __ATOMIC_RELAXED,
                         __HIP_MEMORY_SCOPE_AGENT);
    }
    gbar(t + 2);
  }

  {
    const unsigned short* h0t = h0r + 255ull * 16384;
    const unsigned short* h1p = h1r + 254ull * 16384;
    f32x4 accB = {0.f, 0.f, 0.f, 0.f};
    const unsigned short* ap = (wv < 2) ? h0t : h1p;
    const unsigned short* bm = (wv < 2) ? sm.W1s : sm.U1s;
    int kofs = (wv & 1) * 512;
#pragma unroll
    for (int s8 = 0; s8 < 16; ++s8) {
      int kb = kofs + s8 * 32;
      bf16x8 av = *(const bf16x8*)(ap + lr * HID + kb + kq * 8);
      bf16x8 bv = *(const bf16x8*)&bm[(((kb >> 3) + kq) * 16 + lr) * 8];
      accB = __builtin_amdgcn_mfma_f32_16x16x32_bf16(av, bv, accB, 0, 0, 0);
    }
#pragma unroll
    for (int q = 0; q < 4; ++q) sm.zB[wv][kq * 4 + q][lr] = accB[q];
    __syncthreads();
    if (wv == 0) {
      int b = tid >> 2, u = tid & 3;
      int tok = sm.toks[b][255];
      float z0 = sm.b1s[0 + u]  + sm.zB[0][b][0 + u]  + sm.zB[1][b][0 + u]  + sm.zB[2][b][0 + u]  + sm.zB[3][b][0 + u];
      float z1 = sm.b1s[4 + u]  + sm.zB[0][b][4 + u]  + sm.zB[1][b][4 + u]  + sm.zB[2][b][4 + u]  + sm.zB[3][b][4 + u];
      float z2 = sm.b1s[8 + u]  + sm.zB[0][b][8 + u]  + sm.zB[1][b][8 + u]  + sm.zB[2][b][8 + u]  + sm.zB[3][b][8 + u];
      float z3 = sm.b1s[12 + u] + sm.zB[0][b][12 + u] + sm.zB[1][b][12 + u] + sm.zB[2][b][12 + u] + sm.zB[3][b][12 + u];
      float ii = 1.f / (1.f + expf(-z0));
      float ff = 1.f / (1.f + expf(-z1));
      float gg = tanhf(z2);
      float oo = 1.f / (1.f + expf(-z3));
      float cold = sm.c1[b][u], hold = sm.h1f[b][u];
      float cn = ff * cold + ii * gg;
      float hn = oo * tanhf(cn);
      if (tok == 0) { cn = cold; hn = hold; }
      sm.c1[b][u] = cn; sm.h1f[b][u] = hn;
      h1r[255ull * 16384 + b * HID + bid * 4 + u] = f2bf(hn); // plain: kernel-end flush
    }
    __syncthreads();
  }

  if (tid < 64) {
    int b = tid >> 2, u = tid & 3, ug = bid * 4 + u;
    outHC[OUT_H + (size_t)b * HID + ug]         = sm.h0f[b][u];
    outHC[OUT_H + 16384 + (size_t)b * HID + ug] = sm.h1f[b][u];
    outHC[OUT_H + 32768 + (size_t)b * HID + ug] = sm.c0[b][u];
    outHC[OUT_H + 49152 + (size_t)b * HID + ug] = sm.c1[b][u];
  }
}

extern "C" void kernel_launch(void* const* d_in, const int* in_sizes, int n_in,
                              void* d_out, int out_size, void* d_ws, size_t ws_size,
                              hipStream_t stream) {
  const int*   tokens = (const int*)d_in[0];
  const float* emb = (const float*)d_in[1];
  const float* W0  = (const float*)d_in[2];
  const float* U0  = (const float*)d_in[3];
  const float* b0  = (const float*)d_in[4];
  const float* W1  = (const float*)d_in[5];
  const float* U1  = (const float*)d_in[6];
  const float* b1  = (const float*)d_in[7];
  const float* Wd  = (const float*)d_in[8];
  const float* bd  = (const float*)d_in[9];
  float* out = (float*)d_out;

  char* ws = (char*)d_ws;
  size_t off = 0;
  auto alloc = [&](size_t bytes) { char* p = ws + off; off += (bytes + 255) & ~(size_t)255; return p; };
  unsigned short* W0T = (unsigned short*)alloc(4096ull * 512 * 2);
  unsigned short* U0T = (unsigned short*)alloc(4096ull * 1024 * 2);
  unsigned short* W1T = (unsigned short*)alloc(4096ull * 1024 * 2);
  unsigned short* U1T = (unsigned short*)alloc(4096ull * 1024 * 2);
  unsigned short* WdT = (unsigned short*)alloc(32000ull * 1024 * 2);
  unsigned short* Xg  = (unsigned short*)alloc(4096ull * 512 * 2);
  int*   bar   = (int*)alloc(16384);
  float* Mpart = (float*)alloc(4096ull * 125 * 4);
  float* Spart = (float*)alloc(4096ull * 125 * 4);
  float* MS    = (float*)alloc(4096ull * 2 * 4);
  unsigned short* Lb = (unsigned short*)alloc(4096ull * VOCAB * 2);

  float* XW = out; // 64 MB scratch inside probs region (dead before apply writes)
  unsigned short* h0r = (unsigned short*)((char*)d_out + 192ull * 1024 * 1024);
  unsigned short* h1r = (unsigned short*)((char*)d_out + 208ull * 1024 * 1024);

  hipMemsetAsync(bar, 0, 16384, stream);

  hipFuncSetAttribute((const void*)k_lstm, hipFuncAttributeMaxDynamicSharedMemorySize,
                      (int)sizeof(LstmSmem));
  hipFuncSetAttribute((const void*)k_gemm256<false, false, false>,
                      hipFuncAttributeMaxDynamicSharedMemorySize, 131072);
  hipFuncSetAttribute((const void*)k_gemm256<true, true, true>,
                      hipFuncAttributeMaxDynamicSharedMemorySize, 131072);

  k_transpose_bf16<<<dim3(64, 8), 256, 0, stream>>>(W0, W0T, 512, 4096);
  k_transpose3<<<dim3(64, 16, 3), 256, 0, stream>>>(U0, W1, U1, U0T, W1T, U1T);
  k_transpose_bf16<<<dim3(500, 16), 256, 0, stream>>>(Wd, WdT, 1024, 32000);
  k_gather_emb<<<4096, 256, 0, stream>>>(tokens, emb, Xg);

  // XW[s*16+b][4096] = x @ W0 + b0  (8-phase 256^2, f32 out)
  k_gemm256<false, false, false><<<dim3(16, 16), 512, 131072, stream>>>(
      Xg, W0T, XW, nullptr, b0, 4096, 4096, 512, nullptr, nullptr, 0);

  k_lstm<<<256, 256, sizeof(LstmSmem), stream>>>(tokens, XW, U0T, W1T, U1T, b1,
                                                 h0r, h1r, out, bar);

  // logits(b*256+t) = h1r(t*16+b) @ Wd + bd  (8-phase 256^2, bf16 out + partials, remap)
  k_gemm256<true, true, true><<<dim3(125, 16), 512, 131072, stream>>>(
      h1r, WdT, nullptr, Lb, bd, 4096, 32000, 1024, Mpart, Spart, 125);
  k_sm_combine<<<1024, 256, 0, stream>>>(Mpart, Spart, MS, 125);
  k_sm_apply_bf16<<<4096, 256, 0, stream>>>(Lb, out, MS);
}